// Round 2
// baseline (382.872 us; speedup 1.0000x reference)
//
#include <hip/hip_runtime.h>
#include <math.h>

#define NB 4
#define NC 64
#define NN 4096
#define NH 4

// ---------- async global->LDS (16B per lane, wave-uniform LDS base) ----------
__device__ __forceinline__ void gld16(const float* g, float* l) {
    __builtin_amdgcn_global_load_lds(
        (const __attribute__((address_space(1))) unsigned int*)g,
        (__attribute__((address_space(3))) unsigned int*)l,
        16, 0, 0);
}

// ---------- top-5 insertion helpers (all static indexing) ----------
__device__ __forceinline__ void ins5(float (&tv)[5], int (&ti)[5], float v, int m) {
    // strict > : equal values keep earlier (smaller) index, candidates arrive in ascending m
    if (v > tv[4]) {
        if (v > tv[3]) {
            tv[4]=tv[3]; ti[4]=ti[3];
            if (v > tv[2]) {
                tv[3]=tv[2]; ti[3]=ti[2];
                if (v > tv[1]) {
                    tv[2]=tv[1]; ti[2]=ti[1];
                    if (v > tv[0]) { tv[1]=tv[0]; ti[1]=ti[0]; tv[0]=v; ti[0]=m; }
                    else          { tv[1]=v; ti[1]=m; }
                } else { tv[2]=v; ti[2]=m; }
            } else { tv[3]=v; ti[3]=m; }
        } else { tv[4]=v; ti[4]=m; }
    }
}

__device__ __forceinline__ bool gtt(float v, int m, float v2, int m2) {
    return (v > v2) || ((v == v2) && (m < m2));
}

__device__ __forceinline__ void ins5t(float (&tv)[5], int (&ti)[5], float v, int m) {
    if (gtt(v,m,tv[4],ti[4])) {
        if (gtt(v,m,tv[3],ti[3])) {
            tv[4]=tv[3]; ti[4]=ti[3];
            if (gtt(v,m,tv[2],ti[2])) {
                tv[3]=tv[2]; ti[3]=ti[2];
                if (gtt(v,m,tv[1],ti[1])) {
                    tv[2]=tv[1]; ti[2]=ti[1];
                    if (gtt(v,m,tv[0],ti[0])) { tv[1]=tv[0]; ti[1]=ti[0]; tv[0]=v; ti[0]=m; }
                    else { tv[1]=v; ti[1]=m; }
                } else { tv[2]=v; ti[2]=m; }
            } else { tv[3]=v; ti[3]=m; }
        } else { tv[4]=v; ti[4]=m; }
    }
}

// ---------- K1: channel-l2-normalize x -> xn (b,c,n) ----------
__global__ __launch_bounds__(256) void k_xnorm(const float* __restrict__ x, float* __restrict__ xn) {
    int t = blockIdx.x*256 + threadIdx.x;        // (b,n)
    int b = t >> 12, n = t & (NN-1);
    const float* xb = x + (size_t)b*NC*NN + n;
    float vals[64];
    float ss = 0.f;
    #pragma unroll
    for (int c = 0; c < NC; ++c) { vals[c] = xb[(size_t)c*NN]; ss += vals[c]*vals[c]; }
    float rn = 1.f / fmaxf(sqrtf(ss), 1e-12f);
    float* xo = xn + (size_t)b*NC*NN + n;
    #pragma unroll
    for (int c = 0; c < NC; ++c) xo[(size_t)c*NN] = vals[c]*rn;
}

// ---------- K2: q/k/v projections; output layout (b,h,n,f), f contiguous ----------
__global__ __launch_bounds__(256) void k_qkv(
    const float* __restrict__ x,
    const float* __restrict__ wk, const float* __restrict__ bk,
    const float* __restrict__ wq, const float* __restrict__ bq,
    const float* __restrict__ wv, const float* __restrict__ bv,
    float* __restrict__ qo, float* __restrict__ ko, float* __restrict__ vo)
{
    int blk = blockIdx.x;
    int nt  = blk & 63;
    int rem = blk >> 6;          // 0..47
    int ot  = rem % 12;
    int b   = rem / 12;
    int mat = ot >> 2, h = ot & 3;
    const float* w    = (mat==0) ? wk : ((mat==1) ? wq : wv);
    const float* bias = (mat==0) ? bk : ((mat==1) ? bq : bv);
    float* outp       = (mat==0) ? ko : ((mat==1) ? qo : vo);

    __shared__ __align__(16) float As[64*68];   // [c][f]
    __shared__ __align__(16) float Bs[64*68];   // [c][nl]
    int t = threadIdx.x;
    int n0 = nt*64;
    {   // stage transposed weight tile
        int f = t >> 2, q4 = t & 3;
        #pragma unroll
        for (int s = 0; s < 4; ++s) {
            int c0 = q4*16 + s*4;
            float4 w4 = *(const float4*)(w + (size_t)(h*64+f)*64 + c0);
            As[(c0+0)*68+f] = w4.x; As[(c0+1)*68+f] = w4.y;
            As[(c0+2)*68+f] = w4.z; As[(c0+3)*68+f] = w4.w;
        }
    }
    {   // stage x tile
        int u = t & 15, cb = t >> 4;
        #pragma unroll
        for (int s = 0; s < 4; ++s) {
            int c = cb + 16*s;
            float4 x4 = *(const float4*)(x + ((size_t)b*NC + c)*NN + n0 + u*4);
            *(float4*)&Bs[c*68 + u*4] = x4;
        }
    }
    __syncthreads();
    int tr = t >> 4, tc = t & 15;
    float acc[4][4];
    #pragma unroll
    for (int i=0;i<4;++i) {
        float bb = bias[h*64 + tr*4 + i];
        #pragma unroll
        for (int j=0;j<4;++j) acc[i][j] = bb;
    }
    #pragma unroll 8
    for (int c = 0; c < 64; ++c) {
        float4 a4 = *(const float4*)&As[c*68 + tr*4];
        float4 b4 = *(const float4*)&Bs[c*68 + tc*4];
        float av[4]  = {a4.x,a4.y,a4.z,a4.w};
        float bvv[4] = {b4.x,b4.y,b4.z,b4.w};
        #pragma unroll
        for (int i=0;i<4;++i)
            #pragma unroll
            for (int j=0;j<4;++j)
                acc[i][j] += av[i]*bvv[j];
    }
    float* ob = outp + (((size_t)(b*NH + h))*NN + n0)*64;
    #pragma unroll
    for (int j=0;j<4;++j) {
        float4 o4 = make_float4(acc[0][j], acc[1][j], acc[2][j], acc[3][j]);
        *(float4*)(ob + (size_t)(tc*4+j)*64 + tr*4) = o4;   // [n][f], f contiguous
    }
}

// ---------- K2b: in-place l2norm over f for q and k ----------
__global__ __launch_bounds__(256) void k_l2norm(float* __restrict__ qo, float* __restrict__ ko) {
    int t = blockIdx.x*256 + threadIdx.x;        // 0..131071
    float* base = ((t & 65536) ? ko : qo) + (size_t)(t & 65535)*64;
    float4 vb[16];
    float ss = 0.f;
    #pragma unroll
    for (int i = 0; i < 16; ++i) {
        vb[i] = *(const float4*)(base + i*4);
        ss += vb[i].x*vb[i].x + vb[i].y*vb[i].y + vb[i].z*vb[i].z + vb[i].w*vb[i].w;
    }
    float rn = 1.f / fmaxf(sqrtf(ss), 1e-12f);
    #pragma unroll
    for (int i = 0; i < 16; ++i) {
        vb[i].x*=rn; vb[i].y*=rn; vb[i].z*=rn; vb[i].w*=rn;
        *(float4*)(base + i*4) = vb[i];
    }
}

// ---------- K3: fused sim GEMM + per-row top-5 ----------
// 128 rows x 1024 cols per block; grid = 4b * 32rt * 4cq = 512 -> 2 blocks/CU.
// LDS = As[64][128] + Bs[64][128] = 64 KB exactly. Staged via global_load_lds.
// B fragment reads at 16B stride (tc*4 and 64+tc*4) -> 2 lanes/bank -> conflict-free.
__global__ __launch_bounds__(256, 2) void k_topk(const float* __restrict__ xn,
                                                 float* __restrict__ pv, int* __restrict__ pi)
{
    __shared__ __align__(16) float As[64*128];
    __shared__ __align__(16) float Bs[64*128];
    int blk = blockIdx.x;
    int cq = blk & 3;
    int rt = (blk >> 2) & 31;
    int b  = blk >> 7;
    int rowbase = rt*128;
    int colq = cq*1024;
    const float* xb = xn + (size_t)b*NC*NN;
    int t = threadIdx.x;
    int lane = t & 63, wave = t >> 6;
    int lrow  = lane >> 5;          // 0/1
    int lcol4 = (lane & 31) * 4;

    // stage A tile once: As[c][r] = xb[c*NN + rowbase + r]
    #pragma unroll
    for (int i = 0; i < 8; ++i) {
        int cb = wave*16 + i*2;
        gld16(xb + (size_t)(cb + lrow)*NN + rowbase + lcol4, &As[cb*128]);
    }
    // stage B for step 0
    #pragma unroll
    for (int i = 0; i < 8; ++i) {
        int cb = wave*16 + i*2;
        gld16(xb + (size_t)(cb + lrow)*NN + colq + lcol4, &Bs[cb*128]);
    }
    asm volatile("s_waitcnt vmcnt(0)" ::: "memory");
    __syncthreads();

    int tr = t >> 4, tc = t & 15;
    float tv[8][5]; int ti[8][5];
    #pragma unroll
    for (int i=0;i<8;++i)
        #pragma unroll
        for (int kk=0;kk<5;++kk) { tv[i][kk] = -3.0e38f; ti[i][kk] = 0x7fffffff; }

    for (int step = 0; step < 8; ++step) {
        int m0 = colq + step*128;
        float acc[8][8];
        #pragma unroll
        for (int i=0;i<8;++i)
            #pragma unroll
            for (int j=0;j<8;++j) acc[i][j] = 0.f;
        #pragma unroll 4
        for (int c = 0; c < 64; ++c) {
            float4 a0 = *(const float4*)&As[c*128 + tr*8];
            float4 a1 = *(const float4*)&As[c*128 + tr*8 + 4];
            float4 b0 = *(const float4*)&Bs[c*128 + tc*4];
            float4 b1 = *(const float4*)&Bs[c*128 + 64 + tc*4];
            float av[8]  = {a0.x,a0.y,a0.z,a0.w,a1.x,a1.y,a1.z,a1.w};
            float bvv[8] = {b0.x,b0.y,b0.z,b0.w,b1.x,b1.y,b1.z,b1.w};
            #pragma unroll
            for (int i=0;i<8;++i)
                #pragma unroll
                for (int j=0;j<8;++j)
                    acc[i][j] += av[i]*bvv[j];
        }
        // columns owned: m0 + tc*4 + j  (j<4)  and  m0 + 64 + tc*4 + (j-4)  (j>=4)
        #pragma unroll
        for (int i=0;i<8;++i) {
            #pragma unroll
            for (int j=0;j<4;++j)  ins5(tv[i], ti[i], acc[i][j],   m0 + tc*4 + j);
            #pragma unroll
            for (int j=4;j<8;++j)  ins5(tv[i], ti[i], acc[i][j],   m0 + 64 + tc*4 + (j-4));
        }
        if (step < 7) {
            __syncthreads();   // everyone done reading Bs
            #pragma unroll
            for (int i = 0; i < 8; ++i) {
                int cb = wave*16 + i*2;
                gld16(xb + (size_t)(cb + lrow)*NN + (m0 + 128) + lcol4, &Bs[cb*128]);
            }
            asm volatile("s_waitcnt vmcnt(0)" ::: "memory");
            __syncthreads();
        }
    }

    // butterfly merge across the 16 column-threads (lane bits 0..3 == tc)
    #pragma unroll
    for (int m = 1; m < 16; m <<= 1) {
        #pragma unroll
        for (int i=0;i<8;++i) {
            float ov[5]; int oi[5];
            #pragma unroll
            for (int kk=0;kk<5;++kk) {
                ov[kk] = __shfl_xor(tv[i][kk], m);
                oi[kk] = __shfl_xor(ti[i][kk], m);
            }
            #pragma unroll
            for (int kk=0;kk<5;++kk) ins5t(tv[i], ti[i], ov[kk], oi[kk]);
        }
    }
    if (tc == 0) {
        #pragma unroll
        for (int i=0;i<8;++i) {
            int r = rowbase + tr*8 + i;
            size_t base = ((size_t)b*NN + r)*20 + (size_t)cq*5;
            #pragma unroll
            for (int kk=0;kk<5;++kk) { pv[base+kk] = tv[i][kk]; pi[base+kk] = ti[i][kk]; }
        }
    }
}

// ---------- K3b: merge the four column-quarter partials ----------
__global__ __launch_bounds__(256) void k_topkmerge(const float* __restrict__ pv, const int* __restrict__ pi,
                                                   int* __restrict__ idxo)
{
    int t = blockIdx.x*256 + threadIdx.x;   // 0..16383 = (b,n)
    float bv5[5]; int bi5[5];
    #pragma unroll
    for (int kk=0;kk<5;++kk){ bv5[kk]=-3.0e38f; bi5[kk]=0x7fffffff; }
    size_t base = (size_t)t*20;
    #pragma unroll
    for (int e=0;e<20;++e) ins5t(bv5,bi5, pv[base+e], pi[base+e]);
    #pragma unroll
    for (int kk=0;kk<5;++kk) idxo[(size_t)t*5+kk] = bi5[kk];
}

// ---------- K4: fused laplacian(k)·laplacian(v) partial reduction ----------
__global__ __launch_bounds__(256) void k_kv(const float* __restrict__ ko, const float* __restrict__ vo,
                                            const int* __restrict__ idxo, float* __restrict__ part)
{
    int blk = blockIdx.x;                 // bh(16) * chunk(16)
    int chunk = blk & 15, bh = blk >> 4, b = bh >> 2;
    int t = threadIdx.x;
    int f = t & 63, g = t >> 6;
    const float* kb = ko + (size_t)bh*NN*64;
    const float* vb = vo + (size_t)bh*NN*64;
    const int* ib = idxo + (size_t)b*NN*5;
    float acc = 0.f;
    int nbase = chunk*256 + g*64;
    for (int i2 = 0; i2 < 64; ++i2) {
        int n = nbase + i2;
        const int* ip = ib + (size_t)n*5;
        int j0 = ip[0], j1 = ip[1], j2 = ip[2], j3 = ip[3], j4 = ip[4];
        float lk = kb[(size_t)n*64+f] + kb[(size_t)j0*64+f] + kb[(size_t)j1*64+f]
                 + kb[(size_t)j2*64+f] + kb[(size_t)j3*64+f] + kb[(size_t)j4*64+f];
        float lv = vb[(size_t)n*64+f] + vb[(size_t)j0*64+f] + vb[(size_t)j1*64+f]
                 + vb[(size_t)j2*64+f] + vb[(size_t)j3*64+f] + vb[(size_t)j4*64+f];
        acc += lk*lv;
    }
    __shared__ float red[4][64];
    red[g][f] = acc;
    __syncthreads();
    if (t < 64) {
        float s2 = red[0][t] + red[1][t] + red[2][t] + red[3][t];
        part[((size_t)bh*64 + t)*16 + chunk] = s2;
    }
}

// ---------- K5: wps[b][o][hf] = wp[o][hf] * kv[b][hf] ----------
__global__ __launch_bounds__(256) void k_wps(const float* __restrict__ wp, const float* __restrict__ part,
                                             float* __restrict__ wps)
{
    int t = blockIdx.x*256 + threadIdx.x;    // 65536 = b(4)*o(64)*hf(256)
    int b = t >> 14, rem = t & 16383;
    int hf = rem & 255;
    const float* pp = part + ((size_t)b*256 + hf)*16;
    float s = 0.f;
    #pragma unroll
    for (int c2 = 0; c2 < 16; ++c2) s += pp[c2];
    wps[t] = wp[rem] * (s * (1.f/36.f));
}

// ---------- K6: fused (hy·wp) conv + conv1/BN/ReLU + conv2/BN/ReLU ----------
__global__ __launch_bounds__(256) void k_out(
    const float* __restrict__ qo, const float* __restrict__ wpsb, const float* __restrict__ bp,
    const float* __restrict__ w1, const float* __restrict__ b1,
    const float* __restrict__ w2, const float* __restrict__ b2,
    const float* __restrict__ g1, const float* __restrict__ be1,
    const float* __restrict__ m1, const float* __restrict__ v1,
    const float* __restrict__ g2, const float* __restrict__ be2,
    const float* __restrict__ m2, const float* __restrict__ v2,
    float* __restrict__ outp)
{
    int b  = blockIdx.x >> 6;
    int n0 = (blockIdx.x & 63)*64;
    __shared__ __align__(16) float qs[256*68];   // q tile [hf][nl]; later t1 [o][nl]
    __shared__ __align__(16) float ws2[256*68];  // wps [hf][o]; later w1s/w2s [c][o]
    __shared__ __align__(16) float t0[64*68];    // conv_p out [o][nl]; later t2
    int t = threadIdx.x;
    {
        int f = t & 63, sub = t >> 6;
        #pragma unroll
        for (int h = 0; h < 4; ++h) {
            const float* qb = qo + (((size_t)(b*4+h))*NN + n0)*64 + f;
            for (int nl = sub; nl < 64; nl += 4)
                qs[(h*64+f)*68 + nl] = qb[(size_t)nl*64];
        }
    }
    {
        const float* wb = wpsb + (size_t)b*64*256;
        for (int o = 0; o < 64; ++o)
            ws2[t*68 + o] = wb[(size_t)o*256 + t];
    }
    __syncthreads();
    int tr = t >> 4, tc = t & 15;
    float acc[4][4];
    #pragma unroll
    for (int i=0;i<4;++i) {
        float bb = bp[tr*4+i];
        #pragma unroll
        for (int j=0;j<4;++j) acc[i][j] = bb;
    }
    #pragma unroll 8
    for (int hf = 0; hf < 256; ++hf) {
        float4 a4 = *(const float4*)&ws2[hf*68 + tr*4];
        float4 b4 = *(const float4*)&qs[hf*68 + tc*4];
        float av[4]={a4.x,a4.y,a4.z,a4.w}, bvv[4]={b4.x,b4.y,b4.z,b4.w};
        #pragma unroll
        for (int i=0;i<4;++i)
            #pragma unroll
            for (int j=0;j<4;++j)
                acc[i][j] += av[i]*bvv[j];
    }
    #pragma unroll
    for (int i=0;i<4;++i)
        *(float4*)&t0[(tr*4+i)*68 + tc*4] = make_float4(acc[i][0],acc[i][1],acc[i][2],acc[i][3]);
    __syncthreads();
    #pragma unroll
    for (int s = 0; s < 16; ++s) {   // w1 transposed into ws2
        int e = t + 256*s;
        ws2[(e & 63)*68 + (e >> 6)] = w1[e];
    }
    __syncthreads();
    float acc2[4][4];
    #pragma unroll
    for (int i=0;i<4;++i)
        #pragma unroll
        for (int j=0;j<4;++j) acc2[i][j] = 0.f;
    #pragma unroll 8
    for (int c = 0; c < 64; ++c) {
        float4 a4 = *(const float4*)&ws2[c*68 + tr*4];
        float4 b4 = *(const float4*)&t0[c*68 + tc*4];
        float av[4]={a4.x,a4.y,a4.z,a4.w}, bvv[4]={b4.x,b4.y,b4.z,b4.w};
        #pragma unroll
        for (int i=0;i<4;++i)
            #pragma unroll
            for (int j=0;j<4;++j)
                acc2[i][j] += av[i]*bvv[j];
    }
    #pragma unroll
    for (int i=0;i<4;++i) {          // BN1 + ReLU -> t1 (in qs region)
        int o = tr*4+i;
        float sc = g1[o] / sqrtf(v1[o] + 1e-5f);
        float bb = b1[o], mm = m1[o], bt = be1[o];
        float4 r;
        r.x = fmaxf((acc2[i][0]+bb-mm)*sc + bt, 0.f);
        r.y = fmaxf((acc2[i][1]+bb-mm)*sc + bt, 0.f);
        r.z = fmaxf((acc2[i][2]+bb-mm)*sc + bt, 0.f);
        r.w = fmaxf((acc2[i][3]+bb-mm)*sc + bt, 0.f);
        *(float4*)&qs[o*68 + tc*4] = r;
    }
    __syncthreads();
    #pragma unroll
    for (int s = 0; s < 16; ++s) {   // w2 transposed into ws2
        int e = t + 256*s;
        ws2[(e & 63)*68 + (e >> 6)] = w2[e];
    }
    __syncthreads();
    float acc3[4][4];
    #pragma unroll
    for (int i=0;i<4;++i)
        #pragma unroll
        for (int j=0;j<4;++j) acc3[i][j] = 0.f;
    #pragma unroll 8
    for (int c = 0; c < 64; ++c) {
        float4 a4 = *(const float4*)&ws2[c*68 + tr*4];
        float4 b4 = *(const float4*)&qs[c*68 + tc*4];
        float av[4]={a4.x,a4.y,a4.z,a4.w}, bvv[4]={b4.x,b4.y,b4.z,b4.w};
        #pragma unroll
        for (int i=0;i<4;++i)
            #pragma unroll
            for (int j=0;j<4;++j)
                acc3[i][j] += av[i]*bvv[j];
    }
    #pragma unroll
    for (int i=0;i<4;++i) {          // BN2 + ReLU -> t2 (in t0 region)
        int o = tr*4+i;
        float sc = g2[o] / sqrtf(v2[o] + 1e-5f);
        float bb = b2[o], mm = m2[o], bt = be2[o];
        float4 r;
        r.x = fmaxf((acc3[i][0]+bb-mm)*sc + bt, 0.f);
        r.y = fmaxf((acc3[i][1]+bb-mm)*sc + bt, 0.f);
        r.z = fmaxf((acc3[i][2]+bb-mm)*sc + bt, 0.f);
        r.w = fmaxf((acc3[i][3]+bb-mm)*sc + bt, 0.f);
        *(float4*)&t0[o*68 + tc*4] = r;
    }
    __syncthreads();
    float* ob = outp + ((size_t)b*64)*NN + n0;
    #pragma unroll
    for (int s = 0; s < 16; ++s) {
        int e = t + 256*s;
        int o = e >> 6, nl = e & 63;
        ob[(size_t)o*NN + nl] = t0[o*68 + nl];
    }
}

extern "C" void kernel_launch(void* const* d_in, const int* in_sizes, int n_in,
                              void* d_out, int out_size, void* d_ws, size_t ws_size,
                              hipStream_t stream)
{
    (void)in_sizes; (void)n_in; (void)out_size; (void)ws_size;
    const float* x  = (const float*)d_in[0];
    const float* wk = (const float*)d_in[1];
    const float* bk = (const float*)d_in[2];
    const float* wq = (const float*)d_in[3];
    const float* bq = (const float*)d_in[4];
    const float* wv = (const float*)d_in[5];
    const float* bv = (const float*)d_in[6];
    const float* wp = (const float*)d_in[7];
    const float* bp = (const float*)d_in[8];
    const float* w1 = (const float*)d_in[9];
    const float* b1 = (const float*)d_in[10];
    const float* w2 = (const float*)d_in[11];
    const float* b2 = (const float*)d_in[12];
    const float* g1 = (const float*)d_in[13];
    const float* be1= (const float*)d_in[14];
    const float* m1 = (const float*)d_in[15];
    const float* v1 = (const float*)d_in[16];
    const float* g2 = (const float*)d_in[17];
    const float* be2= (const float*)d_in[18];
    const float* m2 = (const float*)d_in[19];
    const float* v2 = (const float*)d_in[20];
    float* out = (float*)d_out;

    float* ws = (float*)d_ws;
    float* xn   = ws;  ws += (size_t)NB*NC*NN;        // 1,048,576
    float* qbuf = ws;  ws += (size_t)NB*NH*NN*64;     // 4,194,304
    float* kbuf = ws;  ws += (size_t)NB*NH*NN*64;
    float* vbuf = ws;  ws += (size_t)NB*NH*NN*64;
    float* wps  = ws;  ws += (size_t)NB*64*256;       // 65,536
    float* part = ws;  ws += (size_t)16*64*16;        // 16,384
    float* pv   = ws;  ws += (size_t)NB*NN*20;        // 327,680
    int*   pi   = (int*)ws;   ws += (size_t)NB*NN*20;
    int*   idxb = (int*)ws;   ws += (size_t)NB*NN*5;

    k_xnorm<<<64, 256, 0, stream>>>(x, xn);
    k_qkv<<<3072, 256, 0, stream>>>(x, wk,bk, wq,bq, wv,bv, qbuf,kbuf,vbuf);
    k_l2norm<<<512, 256, 0, stream>>>(qbuf, kbuf);
    k_topk<<<512, 256, 0, stream>>>(xn, pv, pi);
    k_topkmerge<<<64, 256, 0, stream>>>(pv, pi, idxb);
    k_kv<<<256, 256, 0, stream>>>(kbuf, vbuf, idxb, part);
    k_wps<<<256, 256, 0, stream>>>(wp, part, wps);
    k_out<<<256, 256, 0, stream>>>(qbuf, wps, bp, w1,b1, w2,b2,
                                   g1,be1,m1,v1, g2,be2,m2,v2, out);
}

// Round 3
// 297.485 us; speedup vs baseline: 1.2870x; 1.2870x over previous
//
#include <hip/hip_runtime.h>
#include <math.h>

#define NB 4
#define NC 64
#define NN 4096
#define NH 4

typedef __attribute__((ext_vector_type(8))) short bf16x8;
typedef __attribute__((ext_vector_type(4))) float f32x4;

// ---------- RNE float -> bf16 bits ----------
__device__ __forceinline__ unsigned int bf16rne(float v) {
    unsigned int u = __float_as_uint(v);
    return (u + 0x7fffu + ((u >> 16) & 1u)) >> 16;
}

// ---------- top-5 insertion helpers (all static indexing) ----------
__device__ __forceinline__ void ins5(float (&tv)[5], int (&ti)[5], float v, int m) {
    // strict > : equal values keep earlier (smaller) index, candidates arrive in ascending m
    if (v > tv[4]) {
        if (v > tv[3]) {
            tv[4]=tv[3]; ti[4]=ti[3];
            if (v > tv[2]) {
                tv[3]=tv[2]; ti[3]=ti[2];
                if (v > tv[1]) {
                    tv[2]=tv[1]; ti[2]=ti[1];
                    if (v > tv[0]) { tv[1]=tv[0]; ti[1]=ti[0]; tv[0]=v; ti[0]=m; }
                    else          { tv[1]=v; ti[1]=m; }
                } else { tv[2]=v; ti[2]=m; }
            } else { tv[3]=v; ti[3]=m; }
        } else { tv[4]=v; ti[4]=m; }
    }
}

__device__ __forceinline__ bool gtt(float v, int m, float v2, int m2) {
    return (v > v2) || ((v == v2) && (m < m2));
}

__device__ __forceinline__ void ins5t(float (&tv)[5], int (&ti)[5], float v, int m) {
    if (gtt(v,m,tv[4],ti[4])) {
        if (gtt(v,m,tv[3],ti[3])) {
            tv[4]=tv[3]; ti[4]=ti[3];
            if (gtt(v,m,tv[2],ti[2])) {
                tv[3]=tv[2]; ti[3]=ti[2];
                if (gtt(v,m,tv[1],ti[1])) {
                    tv[2]=tv[1]; ti[2]=ti[1];
                    if (gtt(v,m,tv[0],ti[0])) { tv[1]=tv[0]; ti[1]=ti[0]; tv[0]=v; ti[0]=m; }
                    else { tv[1]=v; ti[1]=m; }
                } else { tv[2]=v; ti[2]=m; }
            } else { tv[3]=v; ti[3]=m; }
        } else { tv[4]=v; ti[4]=m; }
    }
}

// ---------- K1: channel-l2-normalize x -> hi/lo bf16 split in [b][n][c] layout ----------
__global__ __launch_bounds__(256) void k_xsplit(const float* __restrict__ x,
                                                unsigned short* __restrict__ hi,
                                                unsigned short* __restrict__ lo) {
    int t = blockIdx.x*256 + threadIdx.x;        // (b,n)
    int b = t >> 12, n = t & (NN-1);
    const float* xb = x + (size_t)b*NC*NN + n;
    float vals[64];
    float ss = 0.f;
    #pragma unroll
    for (int c = 0; c < NC; ++c) { vals[c] = xb[(size_t)c*NN]; ss += vals[c]*vals[c]; }
    float rn = 1.f / fmaxf(sqrtf(ss), 1e-12f);
    unsigned short* ho = hi + (size_t)t*64;
    unsigned short* lb = lo + (size_t)t*64;
    #pragma unroll
    for (int g = 0; g < 8; ++g) {
        unsigned int hw[4], lw[4];
        #pragma unroll
        for (int p = 0; p < 4; ++p) {
            float v0 = vals[g*8 + p*2]     * rn;
            float v1 = vals[g*8 + p*2 + 1] * rn;
            unsigned int h0 = bf16rne(v0), h1 = bf16rne(v1);
            float r0 = v0 - __uint_as_float(h0 << 16);
            float r1 = v1 - __uint_as_float(h1 << 16);
            unsigned int l0 = bf16rne(r0), l1 = bf16rne(r1);
            hw[p] = h0 | (h1 << 16);
            lw[p] = l0 | (l1 << 16);
        }
        *(uint4*)(ho + g*8) = make_uint4(hw[0], hw[1], hw[2], hw[3]);
        *(uint4*)(lb + g*8) = make_uint4(lw[0], lw[1], lw[2], lw[3]);
    }
}

// ---------- K2: q/k/v projections; output layout (b,h,n,f), f contiguous ----------
__global__ __launch_bounds__(256) void k_qkv(
    const float* __restrict__ x,
    const float* __restrict__ wk, const float* __restrict__ bk,
    const float* __restrict__ wq, const float* __restrict__ bq,
    const float* __restrict__ wv, const float* __restrict__ bv,
    float* __restrict__ qo, float* __restrict__ ko, float* __restrict__ vo)
{
    int blk = blockIdx.x;
    int nt  = blk & 63;
    int rem = blk >> 6;          // 0..47
    int ot  = rem % 12;
    int b   = rem / 12;
    int mat = ot >> 2, h = ot & 3;
    const float* w    = (mat==0) ? wk : ((mat==1) ? wq : wv);
    const float* bias = (mat==0) ? bk : ((mat==1) ? bq : bv);
    float* outp       = (mat==0) ? ko : ((mat==1) ? qo : vo);

    __shared__ __align__(16) float As[64*68];   // [c][f]
    __shared__ __align__(16) float Bs[64*68];   // [c][nl]
    int t = threadIdx.x;
    int n0 = nt*64;
    {   // stage transposed weight tile
        int f = t >> 2, q4 = t & 3;
        #pragma unroll
        for (int s = 0; s < 4; ++s) {
            int c0 = q4*16 + s*4;
            float4 w4 = *(const float4*)(w + (size_t)(h*64+f)*64 + c0);
            As[(c0+0)*68+f] = w4.x; As[(c0+1)*68+f] = w4.y;
            As[(c0+2)*68+f] = w4.z; As[(c0+3)*68+f] = w4.w;
        }
    }
    {   // stage x tile
        int u = t & 15, cb = t >> 4;
        #pragma unroll
        for (int s = 0; s < 4; ++s) {
            int c = cb + 16*s;
            float4 x4 = *(const float4*)(x + ((size_t)b*NC + c)*NN + n0 + u*4);
            *(float4*)&Bs[c*68 + u*4] = x4;
        }
    }
    __syncthreads();
    int tr = t >> 4, tc = t & 15;
    float acc[4][4];
    #pragma unroll
    for (int i=0;i<4;++i) {
        float bb = bias[h*64 + tr*4 + i];
        #pragma unroll
        for (int j=0;j<4;++j) acc[i][j] = bb;
    }
    #pragma unroll 8
    for (int c = 0; c < 64; ++c) {
        float4 a4 = *(const float4*)&As[c*68 + tr*4];
        float4 b4 = *(const float4*)&Bs[c*68 + tc*4];
        float av[4]  = {a4.x,a4.y,a4.z,a4.w};
        float bvv[4] = {b4.x,b4.y,b4.z,b4.w};
        #pragma unroll
        for (int i=0;i<4;++i)
            #pragma unroll
            for (int j=0;j<4;++j)
                acc[i][j] += av[i]*bvv[j];
    }
    float* ob = outp + (((size_t)(b*NH + h))*NN + n0)*64;
    #pragma unroll
    for (int j=0;j<4;++j) {
        float4 o4 = make_float4(acc[0][j], acc[1][j], acc[2][j], acc[3][j]);
        *(float4*)(ob + (size_t)(tc*4+j)*64 + tr*4) = o4;   // [n][f], f contiguous
    }
}

// ---------- K2b: in-place l2norm over f for q and k ----------
__global__ __launch_bounds__(256) void k_l2norm(float* __restrict__ qo, float* __restrict__ ko) {
    int t = blockIdx.x*256 + threadIdx.x;        // 0..131071
    float* base = ((t & 65536) ? ko : qo) + (size_t)(t & 65535)*64;
    float4 vb[16];
    float ss = 0.f;
    #pragma unroll
    for (int i = 0; i < 16; ++i) {
        vb[i] = *(const float4*)(base + i*4);
        ss += vb[i].x*vb[i].x + vb[i].y*vb[i].y + vb[i].z*vb[i].z + vb[i].w*vb[i].w;
    }
    float rn = 1.f / fmaxf(sqrtf(ss), 1e-12f);
    #pragma unroll
    for (int i = 0; i < 16; ++i) {
        vb[i].x*=rn; vb[i].y*=rn; vb[i].z*=rn; vb[i].w*=rn;
        *(float4*)(base + i*4) = vb[i];
    }
}

// ---------- K3: MFMA split-bf16 sim + per-row top-5 ----------
// Grid = b(4) x rowgroup(64) x colquarter(4) = 1024 blocks, 256 thr (4 waves).
// Wave w owns rows rg*64 + w*16 .. +15; iterates 64 col-tiles of 16.
// sim = hi.hi + lo.hi + hi.lo  (lo.lo ~ 2^-18, dropped). No LDS.
// A-frag (M=16,K=32): lane l holds A[l&15][(l>>4)*8 + 0..7] -> contiguous 16B in [n][c] layout.
// C/D: lane l holds D[(l>>4)*4 + i][l&15]  (verified layout, m89/m91).
__global__ __launch_bounds__(256) void k_topk(const unsigned short* __restrict__ hi,
                                              const unsigned short* __restrict__ lo,
                                              float* __restrict__ pv, int* __restrict__ pi)
{
    int blk = blockIdx.x;
    int cq = blk & 3;
    int rg = (blk >> 2) & 63;
    int b  = blk >> 8;
    int t = threadIdx.x, lane = t & 63, wave = t >> 6;
    int ln = lane & 15, kh = lane >> 4;
    const unsigned short* hb = hi + (size_t)b*NN*64;
    const unsigned short* lb = lo + (size_t)b*NN*64;

    int arow = rg*64 + wave*16 + ln;
    bf16x8 ah0 = *(const bf16x8*)(hb + (size_t)arow*64 + kh*8);
    bf16x8 ah1 = *(const bf16x8*)(hb + (size_t)arow*64 + 32 + kh*8);
    bf16x8 al0 = *(const bf16x8*)(lb + (size_t)arow*64 + kh*8);
    bf16x8 al1 = *(const bf16x8*)(lb + (size_t)arow*64 + 32 + kh*8);

    float tv[4][5]; int ti[4][5];
    #pragma unroll
    for (int i=0;i<4;++i)
        #pragma unroll
        for (int kk=0;kk<5;++kk) { tv[i][kk] = -3.0e38f; ti[i][kk] = 0x7fffffff; }

    int colbase = cq*1024;
    #pragma unroll 2
    for (int t5 = 0; t5 < 64; ++t5) {
        int m0 = colbase + t5*16;
        const unsigned short* bp = hb + (size_t)(m0 + ln)*64 + kh*8;
        const unsigned short* lp = lb + (size_t)(m0 + ln)*64 + kh*8;
        bf16x8 bh0 = *(const bf16x8*)(bp);
        bf16x8 bh1 = *(const bf16x8*)(bp + 32);
        bf16x8 bl0 = *(const bf16x8*)(lp);
        bf16x8 bl1 = *(const bf16x8*)(lp + 32);
        f32x4 acc = {0.f, 0.f, 0.f, 0.f};
        acc = __builtin_amdgcn_mfma_f32_16x16x32_bf16(ah0, bh0, acc, 0,0,0);
        acc = __builtin_amdgcn_mfma_f32_16x16x32_bf16(ah1, bh1, acc, 0,0,0);
        acc = __builtin_amdgcn_mfma_f32_16x16x32_bf16(al0, bh0, acc, 0,0,0);
        acc = __builtin_amdgcn_mfma_f32_16x16x32_bf16(al1, bh1, acc, 0,0,0);
        acc = __builtin_amdgcn_mfma_f32_16x16x32_bf16(ah0, bl0, acc, 0,0,0);
        acc = __builtin_amdgcn_mfma_f32_16x16x32_bf16(ah1, bl1, acc, 0,0,0);
        int col = m0 + ln;   // this lane's column; ascending over t5
        ins5(tv[0], ti[0], acc[0], col);
        ins5(tv[1], ti[1], acc[1], col);
        ins5(tv[2], ti[2], acc[2], col);
        ins5(tv[3], ti[3], acc[3], col);
    }

    // butterfly merge across the 16 column-lanes (lane bits 0..3 = ln)
    #pragma unroll
    for (int m = 1; m < 16; m <<= 1) {
        #pragma unroll
        for (int i=0;i<4;++i) {
            float ov[5]; int oi[5];
            #pragma unroll
            for (int kk=0;kk<5;++kk) {
                ov[kk] = __shfl_xor(tv[i][kk], m);
                oi[kk] = __shfl_xor(ti[i][kk], m);
            }
            #pragma unroll
            for (int kk=0;kk<5;++kk) ins5t(tv[i], ti[i], ov[kk], oi[kk]);
        }
    }
    if (ln == 0) {
        #pragma unroll
        for (int i=0;i<4;++i) {
            int r = rg*64 + wave*16 + kh*4 + i;    // C/D row for this lane/reg
            size_t base = (((size_t)b*NN + r)*4 + cq)*5;
            #pragma unroll
            for (int kk=0;kk<5;++kk) { pv[base+kk] = tv[i][kk]; pi[base+kk] = ti[i][kk]; }
        }
    }
}

// ---------- K3b: merge the four column-quarter partials ----------
__global__ __launch_bounds__(256) void k_topkmerge(const float* __restrict__ pv, const int* __restrict__ pi,
                                                   int* __restrict__ idxo)
{
    int t = blockIdx.x*256 + threadIdx.x;   // 0..16383 = (b,n)
    float bv5[5]; int bi5[5];
    #pragma unroll
    for (int kk=0;kk<5;++kk){ bv5[kk]=-3.0e38f; bi5[kk]=0x7fffffff; }
    size_t base = (size_t)t*20;
    #pragma unroll
    for (int e=0;e<20;++e) ins5t(bv5,bi5, pv[base+e], pi[base+e]);
    #pragma unroll
    for (int kk=0;kk<5;++kk) idxo[(size_t)t*5+kk] = bi5[kk];
}

// ---------- K4: fused laplacian(k)·laplacian(v) partial reduction ----------
__global__ __launch_bounds__(256) void k_kv(const float* __restrict__ ko, const float* __restrict__ vo,
                                            const int* __restrict__ idxo, float* __restrict__ part)
{
    int blk = blockIdx.x;                 // bh(16) * chunk(16)
    int chunk = blk & 15, bh = blk >> 4, b = bh >> 2;
    int t = threadIdx.x;
    int f = t & 63, g = t >> 6;
    const float* kb = ko + (size_t)bh*NN*64;
    const float* vb = vo + (size_t)bh*NN*64;
    const int* ib = idxo + (size_t)b*NN*5;
    float acc = 0.f;
    int nbase = chunk*256 + g*64;
    for (int i2 = 0; i2 < 64; ++i2) {
        int n = nbase + i2;
        const int* ip = ib + (size_t)n*5;
        int j0 = ip[0], j1 = ip[1], j2 = ip[2], j3 = ip[3], j4 = ip[4];
        float lk = kb[(size_t)n*64+f] + kb[(size_t)j0*64+f] + kb[(size_t)j1*64+f]
                 + kb[(size_t)j2*64+f] + kb[(size_t)j3*64+f] + kb[(size_t)j4*64+f];
        float lv = vb[(size_t)n*64+f] + vb[(size_t)j0*64+f] + vb[(size_t)j1*64+f]
                 + vb[(size_t)j2*64+f] + vb[(size_t)j3*64+f] + vb[(size_t)j4*64+f];
        acc += lk*lv;
    }
    __shared__ float red[4][64];
    red[g][f] = acc;
    __syncthreads();
    if (t < 64) {
        float s2 = red[0][t] + red[1][t] + red[2][t] + red[3][t];
        part[((size_t)bh*64 + t)*16 + chunk] = s2;
    }
}

// ---------- K5: wps[b][o][hf] = wp[o][hf] * kv[b][hf] ----------
__global__ __launch_bounds__(256) void k_wps(const float* __restrict__ wp, const float* __restrict__ part,
                                             float* __restrict__ wps)
{
    int t = blockIdx.x*256 + threadIdx.x;    // 65536 = b(4)*o(64)*hf(256)
    int b = t >> 14, rem = t & 16383;
    int hf = rem & 255;
    const float* pp = part + ((size_t)b*256 + hf)*16;
    float s = 0.f;
    #pragma unroll
    for (int c2 = 0; c2 < 16; ++c2) s += pp[c2];
    wps[t] = wp[rem] * (s * (1.f/36.f));
}

// ---------- K6: fused (hy·wp) conv + conv1/BN/ReLU + conv2/BN/ReLU ----------
__global__ __launch_bounds__(256) void k_out(
    const float* __restrict__ qo, const float* __restrict__ wpsb, const float* __restrict__ bp,
    const float* __restrict__ w1, const float* __restrict__ b1,
    const float* __restrict__ w2, const float* __restrict__ b2,
    const float* __restrict__ g1, const float* __restrict__ be1,
    const float* __restrict__ m1, const float* __restrict__ v1,
    const float* __restrict__ g2, const float* __restrict__ be2,
    const float* __restrict__ m2, const float* __restrict__ v2,
    float* __restrict__ outp)
{
    int b  = blockIdx.x >> 6;
    int n0 = (blockIdx.x & 63)*64;
    __shared__ __align__(16) float qs[256*68];   // q tile [hf][nl]; later t1 [o][nl]
    __shared__ __align__(16) float ws2[256*68];  // wps [hf][o]; later w1s/w2s [c][o]
    __shared__ __align__(16) float t0[64*68];    // conv_p out [o][nl]; later t2
    int t = threadIdx.x;
    {
        int f = t & 63, sub = t >> 6;
        #pragma unroll
        for (int h = 0; h < 4; ++h) {
            const float* qb = qo + (((size_t)(b*4+h))*NN + n0)*64 + f;
            for (int nl = sub; nl < 64; nl += 4)
                qs[(h*64+f)*68 + nl] = qb[(size_t)nl*64];
        }
    }
    {
        const float* wb = wpsb + (size_t)b*64*256;
        for (int o = 0; o < 64; ++o)
            ws2[t*68 + o] = wb[(size_t)o*256 + t];
    }
    __syncthreads();
    int tr = t >> 4, tc = t & 15;
    float acc[4][4];
    #pragma unroll
    for (int i=0;i<4;++i) {
        float bb = bp[tr*4+i];
        #pragma unroll
        for (int j=0;j<4;++j) acc[i][j] = bb;
    }
    #pragma unroll 8
    for (int hf = 0; hf < 256; ++hf) {
        float4 a4 = *(const float4*)&ws2[hf*68 + tr*4];
        float4 b4 = *(const float4*)&qs[hf*68 + tc*4];
        float av[4]={a4.x,a4.y,a4.z,a4.w}, bvv[4]={b4.x,b4.y,b4.z,b4.w};
        #pragma unroll
        for (int i=0;i<4;++i)
            #pragma unroll
            for (int j=0;j<4;++j)
                acc[i][j] += av[i]*bvv[j];
    }
    #pragma unroll
    for (int i=0;i<4;++i)
        *(float4*)&t0[(tr*4+i)*68 + tc*4] = make_float4(acc[i][0],acc[i][1],acc[i][2],acc[i][3]);
    __syncthreads();
    #pragma unroll
    for (int s = 0; s < 16; ++s) {   // w1 transposed into ws2
        int e = t + 256*s;
        ws2[(e & 63)*68 + (e >> 6)] = w1[e];
    }
    __syncthreads();
    float acc2[4][4];
    #pragma unroll
    for (int i=0;i<4;++i)
        #pragma unroll
        for (int j=0;j<4;++j) acc2[i][j] = 0.f;
    #pragma unroll 8
    for (int c = 0; c < 64; ++c) {
        float4 a4 = *(const float4*)&ws2[c*68 + tr*4];
        float4 b4 = *(const float4*)&t0[c*68 + tc*4];
        float av[4]={a4.x,a4.y,a4.z,a4.w}, bvv[4]={b4.x,b4.y,b4.z,b4.w};
        #pragma unroll
        for (int i=0;i<4;++i)
            #pragma unroll
            for (int j=0;j<4;++j)
                acc2[i][j] += av[i]*bvv[j];
    }
    #pragma unroll
    for (int i=0;i<4;++i) {          // BN1 + ReLU -> t1 (in qs region)
        int o = tr*4+i;
        float sc = g1[o] / sqrtf(v1[o] + 1e-5f);
        float bb = b1[o], mm = m1[o], bt = be1[o];
        float4 r;
        r.x = fmaxf((acc2[i][0]+bb-mm)*sc + bt, 0.f);
        r.y = fmaxf((acc2[i][1]+bb-mm)*sc + bt, 0.f);
        r.z = fmaxf((acc2[i][2]+bb-mm)*sc + bt, 0.f);
        r.w = fmaxf((acc2[i][3]+bb-mm)*sc + bt, 0.f);
        *(float4*)&qs[o*68 + tc*4] = r;
    }
    __syncthreads();
    #pragma unroll
    for (int s = 0; s < 16; ++s) {   // w2 transposed into ws2
        int e = t + 256*s;
        ws2[(e & 63)*68 + (e >> 6)] = w2[e];
    }
    __syncthreads();
    float acc3[4][4];
    #pragma unroll
    for (int i=0;i<4;++i)
        #pragma unroll
        for (int j=0;j<4;++j) acc3[i][j] = 0.f;
    #pragma unroll 8
    for (int c = 0; c < 64; ++c) {
        float4 a4 = *(const float4*)&ws2[c*68 + tr*4];
        float4 b4 = *(const float4*)&qs[c*68 + tc*4];
        float av[4]={a4.x,a4.y,a4.z,a4.w}, bvv[4]={b4.x,b4.y,b4.z,b4.w};
        #pragma unroll
        for (int i=0;i<4;++i)
            #pragma unroll
            for (int j=0;j<4;++j)
                acc3[i][j] += av[i]*bvv[j];
    }
    #pragma unroll
    for (int i=0;i<4;++i) {          // BN2 + ReLU -> t2 (in t0 region)
        int o = tr*4+i;
        float sc = g2[o] / sqrtf(v2[o] + 1e-5f);
        float bb = b2[o], mm = m2[o], bt = be2[o];
        float4 r;
        r.x = fmaxf((acc3[i][0]+bb-mm)*sc + bt, 0.f);
        r.y = fmaxf((acc3[i][1]+bb-mm)*sc + bt, 0.f);
        r.z = fmaxf((acc3[i][2]+bb-mm)*sc + bt, 0.f);
        r.w = fmaxf((acc3[i][3]+bb-mm)*sc + bt, 0.f);
        *(float4*)&t0[o*68 + tc*4] = r;
    }
    __syncthreads();
    float* ob = outp + ((size_t)b*64)*NN + n0;
    #pragma unroll
    for (int s = 0; s < 16; ++s) {
        int e = t + 256*s;
        int o = e >> 6, nl = e & 63;
        ob[(size_t)o*NN + nl] = t0[o*68 + nl];
    }
}

extern "C" void kernel_launch(void* const* d_in, const int* in_sizes, int n_in,
                              void* d_out, int out_size, void* d_ws, size_t ws_size,
                              hipStream_t stream)
{
    (void)in_sizes; (void)n_in; (void)out_size; (void)ws_size;
    const float* x  = (const float*)d_in[0];
    const float* wk = (const float*)d_in[1];
    const float* bk = (const float*)d_in[2];
    const float* wq = (const float*)d_in[3];
    const float* bq = (const float*)d_in[4];
    const float* wv = (const float*)d_in[5];
    const float* bv = (const float*)d_in[6];
    const float* wp = (const float*)d_in[7];
    const float* bp = (const float*)d_in[8];
    const float* w1 = (const float*)d_in[9];
    const float* b1 = (const float*)d_in[10];
    const float* w2 = (const float*)d_in[11];
    const float* b2 = (const float*)d_in[12];
    const float* g1 = (const float*)d_in[13];
    const float* be1= (const float*)d_in[14];
    const float* m1 = (const float*)d_in[15];
    const float* v1 = (const float*)d_in[16];
    const float* g2 = (const float*)d_in[17];
    const float* be2= (const float*)d_in[18];
    const float* m2 = (const float*)d_in[19];
    const float* v2 = (const float*)d_in[20];
    float* out = (float*)d_out;

    float* ws = (float*)d_ws;
    unsigned short* hib = (unsigned short*)ws;  ws += (size_t)NB*NN*64/2;   // 2MB bf16
    unsigned short* lob = (unsigned short*)ws;  ws += (size_t)NB*NN*64/2;   // 2MB bf16
    float* qbuf = ws;  ws += (size_t)NB*NH*NN*64;     // 4,194,304
    float* kbuf = ws;  ws += (size_t)NB*NH*NN*64;
    float* vbuf = ws;  ws += (size_t)NB*NH*NN*64;
    float* wps  = ws;  ws += (size_t)NB*64*256;       // 65,536
    float* part = ws;  ws += (size_t)16*64*16;        // 16,384
    float* pv   = ws;  ws += (size_t)NB*NN*20;        // 327,680
    int*   pi   = (int*)ws;   ws += (size_t)NB*NN*20;
    int*   idxb = (int*)ws;   ws += (size_t)NB*NN*5;

    k_xsplit<<<64, 256, 0, stream>>>(x, hib, lob);
    k_qkv<<<3072, 256, 0, stream>>>(x, wk,bk, wq,bq, wv,bv, qbuf,kbuf,vbuf);
    k_l2norm<<<512, 256, 0, stream>>>(qbuf, kbuf);
    k_topk<<<1024, 256, 0, stream>>>(hib, lob, pv, pi);
    k_topkmerge<<<64, 256, 0, stream>>>(pv, pi, idxb);
    k_kv<<<256, 256, 0, stream>>>(kbuf, vbuf, idxb, part);
    k_wps<<<256, 256, 0, stream>>>(wp, part, wps);
    k_out<<<256, 256, 0, stream>>>(qbuf, wps, bp, w1,b1, w2,b2,
                                   g1,be1,m1,v1, g2,be2,m2,v2, out);
}

// Round 4
// 266.983 us; speedup vs baseline: 1.4341x; 1.1142x over previous
//
#include <hip/hip_runtime.h>
#include <math.h>

#define NB 4
#define NC 64
#define NN 4096
#define NH 4

typedef __attribute__((ext_vector_type(8))) short bf16x8;
typedef __attribute__((ext_vector_type(4))) float f32x4;

// ---------- RNE float -> bf16 bits ----------
__device__ __forceinline__ unsigned int bf16rne(float v) {
    unsigned int u = __float_as_uint(v);
    return (u + 0x7fffu + ((u >> 16) & 1u)) >> 16;
}

// ---------- branchless top-5 insert of packed key (value<<12 | inv-col) ----------
__device__ __forceinline__ void ins5k(unsigned int (&tk)[5], unsigned int key) {
    bool c0 = key > tk[0], c1 = key > tk[1], c2 = key > tk[2],
         c3 = key > tk[3], c4 = key > tk[4];
    tk[4] = c4 ? (c3 ? tk[3] : key) : tk[4];
    tk[3] = c3 ? (c2 ? tk[2] : key) : tk[3];
    tk[2] = c2 ? (c1 ? tk[1] : key) : tk[2];
    tk[1] = c1 ? (c0 ? tk[0] : key) : tk[1];
    tk[0] = c0 ? key : tk[0];
}

// monotonic unsigned mapping of float bits (order-preserving)
__device__ __forceinline__ unsigned int fmono(float v) {
    unsigned int u = __float_as_uint(v);
    return u ^ ((unsigned int)((int)u >> 31) | 0x80000000u);
}

// ---------- K1: channel-l2-normalize x -> hi/lo bf16 split in [b][n][c] layout ----------
__global__ __launch_bounds__(256) void k_xsplit(const float* __restrict__ x,
                                                unsigned short* __restrict__ hi,
                                                unsigned short* __restrict__ lo) {
    int t = blockIdx.x*256 + threadIdx.x;        // (b,n)
    int b = t >> 12, n = t & (NN-1);
    const float* xb = x + (size_t)b*NC*NN + n;
    float vals[64];
    float ss = 0.f;
    #pragma unroll
    for (int c = 0; c < NC; ++c) { vals[c] = xb[(size_t)c*NN]; ss += vals[c]*vals[c]; }
    float rn = 1.f / fmaxf(sqrtf(ss), 1e-12f);
    unsigned short* ho = hi + (size_t)t*64;
    unsigned short* lb = lo + (size_t)t*64;
    #pragma unroll
    for (int g = 0; g < 8; ++g) {
        unsigned int hw[4], lw[4];
        #pragma unroll
        for (int p = 0; p < 4; ++p) {
            float v0 = vals[g*8 + p*2]     * rn;
            float v1 = vals[g*8 + p*2 + 1] * rn;
            unsigned int h0 = bf16rne(v0), h1 = bf16rne(v1);
            float r0 = v0 - __uint_as_float(h0 << 16);
            float r1 = v1 - __uint_as_float(h1 << 16);
            unsigned int l0 = bf16rne(r0), l1 = bf16rne(r1);
            hw[p] = h0 | (h1 << 16);
            lw[p] = l0 | (l1 << 16);
        }
        *(uint4*)(ho + g*8) = make_uint4(hw[0], hw[1], hw[2], hw[3]);
        *(uint4*)(lb + g*8) = make_uint4(lw[0], lw[1], lw[2], lw[3]);
    }
}

// ---------- K2: q/k/v projections; output layout (b,h,n,f), f contiguous ----------
__global__ __launch_bounds__(256) void k_qkv(
    const float* __restrict__ x,
    const float* __restrict__ wk, const float* __restrict__ bk,
    const float* __restrict__ wq, const float* __restrict__ bq,
    const float* __restrict__ wv, const float* __restrict__ bv,
    float* __restrict__ qo, float* __restrict__ ko, float* __restrict__ vo)
{
    int blk = blockIdx.x;
    int nt  = blk & 63;
    int rem = blk >> 6;          // 0..47
    int ot  = rem % 12;
    int b   = rem / 12;
    int mat = ot >> 2, h = ot & 3;
    const float* w    = (mat==0) ? wk : ((mat==1) ? wq : wv);
    const float* bias = (mat==0) ? bk : ((mat==1) ? bq : bv);
    float* outp       = (mat==0) ? ko : ((mat==1) ? qo : vo);

    __shared__ __align__(16) float As[64*68];   // [c][f]
    __shared__ __align__(16) float Bs[64*68];   // [c][nl]
    int t = threadIdx.x;
    int n0 = nt*64;
    {   // stage transposed weight tile
        int f = t >> 2, q4 = t & 3;
        #pragma unroll
        for (int s = 0; s < 4; ++s) {
            int c0 = q4*16 + s*4;
            float4 w4 = *(const float4*)(w + (size_t)(h*64+f)*64 + c0);
            As[(c0+0)*68+f] = w4.x; As[(c0+1)*68+f] = w4.y;
            As[(c0+2)*68+f] = w4.z; As[(c0+3)*68+f] = w4.w;
        }
    }
    {   // stage x tile
        int u = t & 15, cb = t >> 4;
        #pragma unroll
        for (int s = 0; s < 4; ++s) {
            int c = cb + 16*s;
            float4 x4 = *(const float4*)(x + ((size_t)b*NC + c)*NN + n0 + u*4);
            *(float4*)&Bs[c*68 + u*4] = x4;
        }
    }
    __syncthreads();
    int tr = t >> 4, tc = t & 15;
    float acc[4][4];
    #pragma unroll
    for (int i=0;i<4;++i) {
        float bb = bias[h*64 + tr*4 + i];
        #pragma unroll
        for (int j=0;j<4;++j) acc[i][j] = bb;
    }
    #pragma unroll 8
    for (int c = 0; c < 64; ++c) {
        float4 a4 = *(const float4*)&As[c*68 + tr*4];
        float4 b4 = *(const float4*)&Bs[c*68 + tc*4];
        float av[4]  = {a4.x,a4.y,a4.z,a4.w};
        float bvv[4] = {b4.x,b4.y,b4.z,b4.w};
        #pragma unroll
        for (int i=0;i<4;++i)
            #pragma unroll
            for (int j=0;j<4;++j)
                acc[i][j] += av[i]*bvv[j];
    }
    float* ob = outp + (((size_t)(b*NH + h))*NN + n0)*64;
    #pragma unroll
    for (int j=0;j<4;++j) {
        float4 o4 = make_float4(acc[0][j], acc[1][j], acc[2][j], acc[3][j]);
        *(float4*)(ob + (size_t)(tc*4+j)*64 + tr*4) = o4;   // [n][f], f contiguous
    }
}

// ---------- K2b: in-place l2norm over f for q and k ----------
__global__ __launch_bounds__(256) void k_l2norm(float* __restrict__ qo, float* __restrict__ ko) {
    int t = blockIdx.x*256 + threadIdx.x;        // 0..131071
    float* base = ((t & 65536) ? ko : qo) + (size_t)(t & 65535)*64;
    float4 vb[16];
    float ss = 0.f;
    #pragma unroll
    for (int i = 0; i < 16; ++i) {
        vb[i] = *(const float4*)(base + i*4);
        ss += vb[i].x*vb[i].x + vb[i].y*vb[i].y + vb[i].z*vb[i].z + vb[i].w*vb[i].w;
    }
    float rn = 1.f / fmaxf(sqrtf(ss), 1e-12f);
    #pragma unroll
    for (int i = 0; i < 16; ++i) {
        vb[i].x*=rn; vb[i].y*=rn; vb[i].z*=rn; vb[i].w*=rn;
        *(float4*)(base + i*4) = vb[i];
    }
}

// ---------- K3: MFMA split-bf16 sim + packed-key branchless top-5 ----------
// Grid = b(4) x rowgroup(64) x coleighth(8) = 2048 blocks, 256 thr (4 waves).
// Wave w owns rows rg*64 + w*16..+15; streams 32 col-tiles of 16, double-buffered.
// key = mono(sim)[31:12] | (4095-col): top-5 by unsigned cmp == (value desc, col asc).
__device__ __forceinline__ void ctile(const bf16x8& ah0, const bf16x8& ah1,
                                      const bf16x8& al0, const bf16x8& al1,
                                      const bf16x8& bh0, const bf16x8& bh1,
                                      const bf16x8& bl0, const bf16x8& bl1,
                                      unsigned int (&tk)[4][5], int col)
{
    f32x4 acc = {0.f, 0.f, 0.f, 0.f};
    acc = __builtin_amdgcn_mfma_f32_16x16x32_bf16(ah0, bh0, acc, 0,0,0);
    acc = __builtin_amdgcn_mfma_f32_16x16x32_bf16(ah1, bh1, acc, 0,0,0);
    acc = __builtin_amdgcn_mfma_f32_16x16x32_bf16(al0, bh0, acc, 0,0,0);
    acc = __builtin_amdgcn_mfma_f32_16x16x32_bf16(al1, bh1, acc, 0,0,0);
    acc = __builtin_amdgcn_mfma_f32_16x16x32_bf16(ah0, bl0, acc, 0,0,0);
    acc = __builtin_amdgcn_mfma_f32_16x16x32_bf16(ah1, bl1, acc, 0,0,0);
    unsigned int inv = 4095u - (unsigned int)col;
    #pragma unroll
    for (int r = 0; r < 4; ++r) {
        unsigned int key = (fmono(acc[r]) & 0xFFFFF000u) | inv;
        ins5k(tk[r], key);
    }
}

__global__ __launch_bounds__(256) void k_topk(const unsigned short* __restrict__ hi,
                                              const unsigned short* __restrict__ lo,
                                              unsigned int* __restrict__ pk)
{
    int blk = blockIdx.x;
    int ce = blk & 7;
    int rg = (blk >> 3) & 63;
    int b  = blk >> 9;
    int t = threadIdx.x, lane = t & 63, wave = t >> 6;
    int ln = lane & 15, kh = lane >> 4;
    const unsigned short* hb = hi + (size_t)b*NN*64;
    const unsigned short* lb = lo + (size_t)b*NN*64;

    int arow = rg*64 + wave*16 + ln;
    bf16x8 ah0 = *(const bf16x8*)(hb + (size_t)arow*64 + kh*8);
    bf16x8 ah1 = *(const bf16x8*)(hb + (size_t)arow*64 + 32 + kh*8);
    bf16x8 al0 = *(const bf16x8*)(lb + (size_t)arow*64 + kh*8);
    bf16x8 al1 = *(const bf16x8*)(lb + (size_t)arow*64 + 32 + kh*8);

    unsigned int tk[4][5];
    #pragma unroll
    for (int r=0;r<4;++r)
        #pragma unroll
        for (int kk=0;kk<5;++kk) tk[r][kk] = 0u;

    int colbase = ce*512;
    // double-buffered B fragments (named regs, static indexing)
    const unsigned short* p0h = hb + (size_t)(colbase + ln)*64 + kh*8;
    const unsigned short* p0l = lb + (size_t)(colbase + ln)*64 + kh*8;
    bf16x8 Ah0 = *(const bf16x8*)(p0h);
    bf16x8 Ah1 = *(const bf16x8*)(p0h + 32);
    bf16x8 Al0 = *(const bf16x8*)(p0l);
    bf16x8 Al1 = *(const bf16x8*)(p0l + 32);
    bf16x8 Bh0, Bh1, Bl0, Bl1;

    for (int t5 = 0; t5 < 32; t5 += 2) {
        {   // prefetch t5+1 into B
            int m = colbase + (t5+1)*16;
            const unsigned short* ph = hb + (size_t)(m + ln)*64 + kh*8;
            const unsigned short* pl = lb + (size_t)(m + ln)*64 + kh*8;
            Bh0 = *(const bf16x8*)(ph);
            Bh1 = *(const bf16x8*)(ph + 32);
            Bl0 = *(const bf16x8*)(pl);
            Bl1 = *(const bf16x8*)(pl + 32);
        }
        ctile(ah0,ah1,al0,al1, Ah0,Ah1,Al0,Al1, tk, colbase + t5*16 + ln);
        {   // prefetch t5+2 into A (clamped on last iter; dummy load, unused)
            int m = (t5+2 < 32) ? (colbase + (t5+2)*16) : colbase;
            const unsigned short* ph = hb + (size_t)(m + ln)*64 + kh*8;
            const unsigned short* pl = lb + (size_t)(m + ln)*64 + kh*8;
            Ah0 = *(const bf16x8*)(ph);
            Ah1 = *(const bf16x8*)(ph + 32);
            Al0 = *(const bf16x8*)(pl);
            Al1 = *(const bf16x8*)(pl + 32);
        }
        ctile(ah0,ah1,al0,al1, Bh0,Bh1,Bl0,Bl1, tk, colbase + (t5+1)*16 + ln);
    }

    // butterfly merge across the 16 column-lanes (lane bits 0..3 = ln)
    #pragma unroll
    for (int m = 1; m < 16; m <<= 1) {
        #pragma unroll
        for (int r=0;r<4;++r) {
            unsigned int ok[5];
            #pragma unroll
            for (int kk=0;kk<5;++kk)
                ok[kk] = (unsigned int)__shfl_xor((int)tk[r][kk], m);
            #pragma unroll
            for (int kk=0;kk<5;++kk) ins5k(tk[r], ok[kk]);
        }
    }
    if (ln == 0) {
        #pragma unroll
        for (int r=0;r<4;++r) {
            int row = rg*64 + wave*16 + kh*4 + r;    // C/D row for this lane/reg
            size_t base = (((size_t)b*NN + row)*8 + ce)*5;
            #pragma unroll
            for (int kk=0;kk<5;++kk) pk[base+kk] = tk[r][kk];
        }
    }
}

// ---------- K3b: merge the eight column-eighth partials ----------
__global__ __launch_bounds__(256) void k_topkmerge(const unsigned int* __restrict__ pk,
                                                   int* __restrict__ idxo)
{
    int t = blockIdx.x*256 + threadIdx.x;   // 0..16383 = (b,n)
    unsigned int bk5[5];
    #pragma unroll
    for (int kk=0;kk<5;++kk) bk5[kk] = 0u;
    size_t base = (size_t)t*40;
    #pragma unroll
    for (int e=0;e<40;++e) ins5k(bk5, pk[base+e]);
    #pragma unroll
    for (int kk=0;kk<5;++kk) idxo[(size_t)t*5+kk] = 4095 - (int)(bk5[kk] & 0xFFFu);
}

// ---------- K4: fused laplacian(k)·laplacian(v) partial reduction ----------
__global__ __launch_bounds__(256) void k_kv(const float* __restrict__ ko, const float* __restrict__ vo,
                                            const int* __restrict__ idxo, float* __restrict__ part)
{
    int blk = blockIdx.x;                 // bh(16) * chunk(16)
    int chunk = blk & 15, bh = blk >> 4, b = bh >> 2;
    int t = threadIdx.x;
    int f = t & 63, g = t >> 6;
    const float* kb = ko + (size_t)bh*NN*64;
    const float* vb = vo + (size_t)bh*NN*64;
    const int* ib = idxo + (size_t)b*NN*5;
    float acc = 0.f;
    int nbase = chunk*256 + g*64;
    for (int i2 = 0; i2 < 64; ++i2) {
        int n = nbase + i2;
        const int* ip = ib + (size_t)n*5;
        int j0 = ip[0], j1 = ip[1], j2 = ip[2], j3 = ip[3], j4 = ip[4];
        float lk = kb[(size_t)n*64+f] + kb[(size_t)j0*64+f] + kb[(size_t)j1*64+f]
                 + kb[(size_t)j2*64+f] + kb[(size_t)j3*64+f] + kb[(size_t)j4*64+f];
        float lv = vb[(size_t)n*64+f] + vb[(size_t)j0*64+f] + vb[(size_t)j1*64+f]
                 + vb[(size_t)j2*64+f] + vb[(size_t)j3*64+f] + vb[(size_t)j4*64+f];
        acc += lk*lv;
    }
    __shared__ float red[4][64];
    red[g][f] = acc;
    __syncthreads();
    if (t < 64) {
        float s2 = red[0][t] + red[1][t] + red[2][t] + red[3][t];
        part[((size_t)bh*64 + t)*16 + chunk] = s2;
    }
}

// ---------- K5: wps[b][o][hf] = wp[o][hf] * kv[b][hf] ----------
__global__ __launch_bounds__(256) void k_wps(const float* __restrict__ wp, const float* __restrict__ part,
                                             float* __restrict__ wps)
{
    int t = blockIdx.x*256 + threadIdx.x;    // 65536 = b(4)*o(64)*hf(256)
    int b = t >> 14, rem = t & 16383;
    int hf = rem & 255;
    const float* pp = part + ((size_t)b*256 + hf)*16;
    float s = 0.f;
    #pragma unroll
    for (int c2 = 0; c2 < 16; ++c2) s += pp[c2];
    wps[t] = wp[rem] * (s * (1.f/36.f));
}

// ---------- K6: fused (hy·wp) conv + conv1/BN/ReLU + conv2/BN/ReLU ----------
__global__ __launch_bounds__(256) void k_out(
    const float* __restrict__ qo, const float* __restrict__ wpsb, const float* __restrict__ bp,
    const float* __restrict__ w1, const float* __restrict__ b1,
    const float* __restrict__ w2, const float* __restrict__ b2,
    const float* __restrict__ g1, const float* __restrict__ be1,
    const float* __restrict__ m1, const float* __restrict__ v1,
    const float* __restrict__ g2, const float* __restrict__ be2,
    const float* __restrict__ m2, const float* __restrict__ v2,
    float* __restrict__ outp)
{
    int b  = blockIdx.x >> 6;
    int n0 = (blockIdx.x & 63)*64;
    __shared__ __align__(16) float qs[256*68];   // q tile [hf][nl]; later t1 [o][nl]
    __shared__ __align__(16) float ws2[256*68];  // wps [hf][o]; later w1s/w2s [c][o]
    __shared__ __align__(16) float t0[64*68];    // conv_p out [o][nl]; later t2
    int t = threadIdx.x;
    {
        int f = t & 63, sub = t >> 6;
        #pragma unroll
        for (int h = 0; h < 4; ++h) {
            const float* qb = qo + (((size_t)(b*4+h))*NN + n0)*64 + f;
            for (int nl = sub; nl < 64; nl += 4)
                qs[(h*64+f)*68 + nl] = qb[(size_t)nl*64];
        }
    }
    {
        const float* wb = wpsb + (size_t)b*64*256;
        for (int o = 0; o < 64; ++o)
            ws2[t*68 + o] = wb[(size_t)o*256 + t];
    }
    __syncthreads();
    int tr = t >> 4, tc = t & 15;
    float acc[4][4];
    #pragma unroll
    for (int i=0;i<4;++i) {
        float bb = bp[tr*4+i];
        #pragma unroll
        for (int j=0;j<4;++j) acc[i][j] = bb;
    }
    #pragma unroll 8
    for (int hf = 0; hf < 256; ++hf) {
        float4 a4 = *(const float4*)&ws2[hf*68 + tr*4];
        float4 b4 = *(const float4*)&qs[hf*68 + tc*4];
        float av[4]={a4.x,a4.y,a4.z,a4.w}, bvv[4]={b4.x,b4.y,b4.z,b4.w};
        #pragma unroll
        for (int i=0;i<4;++i)
            #pragma unroll
            for (int j=0;j<4;++j)
                acc[i][j] += av[i]*bvv[j];
    }
    #pragma unroll
    for (int i=0;i<4;++i)
        *(float4*)&t0[(tr*4+i)*68 + tc*4] = make_float4(acc[i][0],acc[i][1],acc[i][2],acc[i][3]);
    __syncthreads();
    #pragma unroll
    for (int s = 0; s < 16; ++s) {   // w1 transposed into ws2
        int e = t + 256*s;
        ws2[(e & 63)*68 + (e >> 6)] = w1[e];
    }
    __syncthreads();
    float acc2[4][4];
    #pragma unroll
    for (int i=0;i<4;++i)
        #pragma unroll
        for (int j=0;j<4;++j) acc2[i][j] = 0.f;
    #pragma unroll 8
    for (int c = 0; c < 64; ++c) {
        float4 a4 = *(const float4*)&ws2[c*68 + tr*4];
        float4 b4 = *(const float4*)&t0[c*68 + tc*4];
        float av[4]={a4.x,a4.y,a4.z,a4.w}, bvv[4]={b4.x,b4.y,b4.z,b4.w};
        #pragma unroll
        for (int i=0;i<4;++i)
            #pragma unroll
            for (int j=0;j<4;++j)
                acc2[i][j] += av[i]*bvv[j];
    }
    #pragma unroll
    for (int i=0;i<4;++i) {          // BN1 + ReLU -> t1 (in qs region)
        int o = tr*4+i;
        float sc = g1[o] / sqrtf(v1[o] + 1e-5f);
        float bb = b1[o], mm = m1[o], bt = be1[o];
        float4 r;
        r.x = fmaxf((acc2[i][0]+bb-mm)*sc + bt, 0.f);
        r.y = fmaxf((acc2[i][1]+bb-mm)*sc + bt, 0.f);
        r.z = fmaxf((acc2[i][2]+bb-mm)*sc + bt, 0.f);
        r.w = fmaxf((acc2[i][3]+bb-mm)*sc + bt, 0.f);
        *(float4*)&qs[o*68 + tc*4] = r;
    }
    __syncthreads();
    #pragma unroll
    for (int s = 0; s < 16; ++s) {   // w2 transposed into ws2
        int e = t + 256*s;
        ws2[(e & 63)*68 + (e >> 6)] = w2[e];
    }
    __syncthreads();
    float acc3[4][4];
    #pragma unroll
    for (int i=0;i<4;++i)
        #pragma unroll
        for (int j=0;j<4;++j) acc3[i][j] = 0.f;
    #pragma unroll 8
    for (int c = 0; c < 64; ++c) {
        float4 a4 = *(const float4*)&ws2[c*68 + tr*4];
        float4 b4 = *(const float4*)&qs[c*68 + tc*4];
        float av[4]={a4.x,a4.y,a4.z,a4.w}, bvv[4]={b4.x,b4.y,b4.z,b4.w};
        #pragma unroll
        for (int i=0;i<4;++i)
            #pragma unroll
            for (int j=0;j<4;++j)
                acc3[i][j] += av[i]*bvv[j];
    }
    #pragma unroll
    for (int i=0;i<4;++i) {          // BN2 + ReLU -> t2 (in t0 region)
        int o = tr*4+i;
        float sc = g2[o] / sqrtf(v2[o] + 1e-5f);
        float bb = b2[o], mm = m2[o], bt = be2[o];
        float4 r;
        r.x = fmaxf((acc3[i][0]+bb-mm)*sc + bt, 0.f);
        r.y = fmaxf((acc3[i][1]+bb-mm)*sc + bt, 0.f);
        r.z = fmaxf((acc3[i][2]+bb-mm)*sc + bt, 0.f);
        r.w = fmaxf((acc3[i][3]+bb-mm)*sc + bt, 0.f);
        *(float4*)&t0[o*68 + tc*4] = r;
    }
    __syncthreads();
    float* ob = outp + ((size_t)b*64)*NN + n0;
    #pragma unroll
    for (int s = 0; s < 16; ++s) {
        int e = t + 256*s;
        int o = e >> 6, nl = e & 63;
        ob[(size_t)o*NN + nl] = t0[o*68 + nl];
    }
}

extern "C" void kernel_launch(void* const* d_in, const int* in_sizes, int n_in,
                              void* d_out, int out_size, void* d_ws, size_t ws_size,
                              hipStream_t stream)
{
    (void)in_sizes; (void)n_in; (void)out_size; (void)ws_size;
    const float* x  = (const float*)d_in[0];
    const float* wk = (const float*)d_in[1];
    const float* bk = (const float*)d_in[2];
    const float* wq = (const float*)d_in[3];
    const float* bq = (const float*)d_in[4];
    const float* wv = (const float*)d_in[5];
    const float* bv = (const float*)d_in[6];
    const float* wp = (const float*)d_in[7];
    const float* bp = (const float*)d_in[8];
    const float* w1 = (const float*)d_in[9];
    const float* b1 = (const float*)d_in[10];
    const float* w2 = (const float*)d_in[11];
    const float* b2 = (const float*)d_in[12];
    const float* g1 = (const float*)d_in[13];
    const float* be1= (const float*)d_in[14];
    const float* m1 = (const float*)d_in[15];
    const float* v1 = (const float*)d_in[16];
    const float* g2 = (const float*)d_in[17];
    const float* be2= (const float*)d_in[18];
    const float* m2 = (const float*)d_in[19];
    const float* v2 = (const float*)d_in[20];
    float* out = (float*)d_out;

    float* ws = (float*)d_ws;
    unsigned short* hib = (unsigned short*)ws;  ws += (size_t)NB*NN*64/2;   // 2MB bf16
    unsigned short* lob = (unsigned short*)ws;  ws += (size_t)NB*NN*64/2;   // 2MB bf16
    float* qbuf = ws;  ws += (size_t)NB*NH*NN*64;     // 4,194,304
    float* kbuf = ws;  ws += (size_t)NB*NH*NN*64;
    float* vbuf = ws;  ws += (size_t)NB*NH*NN*64;
    float* wps  = ws;  ws += (size_t)NB*64*256;       // 65,536
    float* part = ws;  ws += (size_t)16*64*16;        // 16,384
    unsigned int* pk = (unsigned int*)ws;  ws += (size_t)NB*NN*40;  // 655,360 u32
    int*   idxb = (int*)ws;   ws += (size_t)NB*NN*5;

    k_xsplit<<<64, 256, 0, stream>>>(x, hib, lob);
    k_qkv<<<3072, 256, 0, stream>>>(x, wk,bk, wq,bq, wv,bv, qbuf,kbuf,vbuf);
    k_l2norm<<<512, 256, 0, stream>>>(qbuf, kbuf);
    k_topk<<<2048, 256, 0, stream>>>(hib, lob, pk);
    k_topkmerge<<<64, 256, 0, stream>>>(pk, idxb);
    k_kv<<<256, 256, 0, stream>>>(kbuf, vbuf, idxb, part);
    k_wps<<<256, 256, 0, stream>>>(wp, part, wps);
    k_out<<<256, 256, 0, stream>>>(qbuf, wps, bp, w1,b1, w2,b2,
                                   g1,be1,m1,v1, g2,be2,m2,v2, out);
}

// Round 5
// 231.002 us; speedup vs baseline: 1.6574x; 1.1558x over previous
//
#include <hip/hip_runtime.h>
#include <math.h>

#define NB 4
#define NC 64
#define NN 4096
#define NH 4

typedef __attribute__((ext_vector_type(8))) short bf16x8;
typedef __attribute__((ext_vector_type(4))) float f32x4;

// ---------- RNE float -> bf16 bits ----------
__device__ __forceinline__ unsigned int bf16rne(float v) {
    unsigned int u = __float_as_uint(v);
    return (u + 0x7fffu + ((u >> 16) & 1u)) >> 16;
}

// ---------- top-5 insert via min/max sorting network (9 VALU, no masks) ----------
__device__ __forceinline__ void ins5k(unsigned int (&tk)[5], unsigned int key) {
    unsigned int hi0 = max(tk[0], key), lo0 = min(tk[0], key); tk[0] = hi0;
    unsigned int hi1 = max(tk[1], lo0), lo1 = min(tk[1], lo0); tk[1] = hi1;
    unsigned int hi2 = max(tk[2], lo1), lo2 = min(tk[2], lo1); tk[2] = hi2;
    unsigned int hi3 = max(tk[3], lo2), lo3 = min(tk[3], lo2); tk[3] = hi3;
    tk[4] = max(tk[4], lo3);
}

// ---------- K1: channel-l2-normalize x -> interleaved [hi(64)|lo(64)] bf16 per node ----------
__global__ __launch_bounds__(256) void k_xsplit(const float* __restrict__ x,
                                                unsigned short* __restrict__ hl) {
    int t = blockIdx.x*256 + threadIdx.x;        // (b,n)
    int b = t >> 12, n = t & (NN-1);
    const float* xb = x + (size_t)b*NC*NN + n;
    float vals[64];
    float ss = 0.f;
    #pragma unroll
    for (int c = 0; c < NC; ++c) { vals[c] = xb[(size_t)c*NN]; ss += vals[c]*vals[c]; }
    float rn = 1.f / fmaxf(sqrtf(ss), 1e-12f);
    unsigned short* ho = hl + (size_t)t*128;
    #pragma unroll
    for (int g = 0; g < 8; ++g) {
        unsigned int hw[4], lw[4];
        #pragma unroll
        for (int p = 0; p < 4; ++p) {
            float v0 = vals[g*8 + p*2]     * rn;
            float v1 = vals[g*8 + p*2 + 1] * rn;
            unsigned int h0 = bf16rne(v0), h1 = bf16rne(v1);
            float r0 = v0 - __uint_as_float(h0 << 16);
            float r1 = v1 - __uint_as_float(h1 << 16);
            unsigned int l0 = bf16rne(r0), l1 = bf16rne(r1);
            hw[p] = h0 | (h1 << 16);
            lw[p] = l0 | (l1 << 16);
        }
        *(uint4*)(ho + g*8)      = make_uint4(hw[0], hw[1], hw[2], hw[3]);
        *(uint4*)(ho + 64 + g*8) = make_uint4(lw[0], lw[1], lw[2], lw[3]);
    }
}

// ---------- K2: q/k/v projections + fused l2norm (q,k); output (b,h,n,f), f contiguous ----------
__global__ __launch_bounds__(256) void k_qkv(
    const float* __restrict__ x,
    const float* __restrict__ wk, const float* __restrict__ bk,
    const float* __restrict__ wq, const float* __restrict__ bq,
    const float* __restrict__ wv, const float* __restrict__ bv,
    float* __restrict__ qo, float* __restrict__ ko, float* __restrict__ vo)
{
    int blk = blockIdx.x;
    int nt  = blk & 63;
    int rem = blk >> 6;          // 0..47
    int ot  = rem % 12;
    int b   = rem / 12;
    int mat = ot >> 2, h = ot & 3;
    const float* w    = (mat==0) ? wk : ((mat==1) ? wq : wv);
    const float* bias = (mat==0) ? bk : ((mat==1) ? bq : bv);
    float* outp       = (mat==0) ? ko : ((mat==1) ? qo : vo);

    __shared__ __align__(16) float As[64*68];   // [c][f]
    __shared__ __align__(16) float Bs[64*68];   // [c][nl]
    __shared__ float redq[16][64];
    __shared__ float rnl[64];
    int t = threadIdx.x;
    int n0 = nt*64;
    {   // stage transposed weight tile
        int f = t >> 2, q4 = t & 3;
        #pragma unroll
        for (int s = 0; s < 4; ++s) {
            int c0 = q4*16 + s*4;
            float4 w4 = *(const float4*)(w + (size_t)(h*64+f)*64 + c0);
            As[(c0+0)*68+f] = w4.x; As[(c0+1)*68+f] = w4.y;
            As[(c0+2)*68+f] = w4.z; As[(c0+3)*68+f] = w4.w;
        }
    }
    {   // stage x tile
        int u = t & 15, cb = t >> 4;
        #pragma unroll
        for (int s = 0; s < 4; ++s) {
            int c = cb + 16*s;
            float4 x4 = *(const float4*)(x + ((size_t)b*NC + c)*NN + n0 + u*4);
            *(float4*)&Bs[c*68 + u*4] = x4;
        }
    }
    __syncthreads();
    int tr = t >> 4, tc = t & 15;
    float acc[4][4];
    #pragma unroll
    for (int i=0;i<4;++i) {
        float bb = bias[h*64 + tr*4 + i];
        #pragma unroll
        for (int j=0;j<4;++j) acc[i][j] = bb;
    }
    #pragma unroll 8
    for (int c = 0; c < 64; ++c) {
        float4 a4 = *(const float4*)&As[c*68 + tr*4];
        float4 b4 = *(const float4*)&Bs[c*68 + tc*4];
        float av[4]  = {a4.x,a4.y,a4.z,a4.w};
        float bvv[4] = {b4.x,b4.y,b4.z,b4.w};
        #pragma unroll
        for (int i=0;i<4;++i)
            #pragma unroll
            for (int j=0;j<4;++j)
                acc[i][j] += av[i]*bvv[j];
    }
    if (mat != 2) {   // fused l2norm over f for q,k
        #pragma unroll
        for (int j=0;j<4;++j) {
            float s2 = acc[0][j]*acc[0][j] + acc[1][j]*acc[1][j]
                     + acc[2][j]*acc[2][j] + acc[3][j]*acc[3][j];
            redq[tr][tc*4+j] = s2;
        }
        __syncthreads();
        if (t < 64) {
            float s2 = 0.f;
            #pragma unroll
            for (int q = 0; q < 16; ++q) s2 += redq[q][t];
            rnl[t] = 1.f / fmaxf(sqrtf(s2), 1e-12f);
        }
        __syncthreads();
        #pragma unroll
        for (int j=0;j<4;++j) {
            float rr = rnl[tc*4+j];
            #pragma unroll
            for (int i=0;i<4;++i) acc[i][j] *= rr;
        }
    }
    float* ob = outp + (((size_t)(b*NH + h))*NN + n0)*64;
    #pragma unroll
    for (int j=0;j<4;++j) {
        float4 o4 = make_float4(acc[0][j], acc[1][j], acc[2][j], acc[3][j]);
        *(float4*)(ob + (size_t)(tc*4+j)*64 + tr*4) = o4;   // [n][f], f contiguous
    }
}

// ---------- K3: MFMA split-bf16 sim + packed-key min/max top-5 ----------
// Grid = b(4) x rowgroup(64) x coleighth(8) = 2048 blocks, 256 thr (4 waves).
// key = bits(sim+2.0)[31:12] | (4095-col) : unsigned cmp == (value desc, col asc).
__device__ __forceinline__ void ctile(const bf16x8& ah0, const bf16x8& ah1,
                                      const bf16x8& al0, const bf16x8& al1,
                                      const bf16x8& bh0, const bf16x8& bh1,
                                      const bf16x8& bl0, const bf16x8& bl1,
                                      unsigned int (&tk)[4][5], unsigned int inv)
{
    f32x4 acc = {0.f, 0.f, 0.f, 0.f};
    acc = __builtin_amdgcn_mfma_f32_16x16x32_bf16(ah0, bh0, acc, 0,0,0);
    acc = __builtin_amdgcn_mfma_f32_16x16x32_bf16(ah1, bh1, acc, 0,0,0);
    acc = __builtin_amdgcn_mfma_f32_16x16x32_bf16(al0, bh0, acc, 0,0,0);
    acc = __builtin_amdgcn_mfma_f32_16x16x32_bf16(al1, bh1, acc, 0,0,0);
    acc = __builtin_amdgcn_mfma_f32_16x16x32_bf16(ah0, bl0, acc, 0,0,0);
    acc = __builtin_amdgcn_mfma_f32_16x16x32_bf16(ah1, bl1, acc, 0,0,0);
    #pragma unroll
    for (int r = 0; r < 4; ++r) {
        unsigned int key = (__float_as_uint(acc[r] + 2.0f) & 0xFFFFF000u) | inv;
        ins5k(tk[r], key);
    }
}

__global__ __launch_bounds__(256) void k_topk(const unsigned short* __restrict__ hl,
                                              unsigned int* __restrict__ pk)
{
    int blk = blockIdx.x;
    int ce = blk & 7;
    int rg = (blk >> 3) & 63;
    int b  = blk >> 9;
    int t = threadIdx.x, lane = t & 63, wave = t >> 6;
    int ln = lane & 15, kh = lane >> 4;
    const unsigned short* hb = hl + (size_t)b*NN*128;

    const unsigned short* ap = hb + (size_t)(rg*64 + wave*16 + ln)*128 + kh*8;
    bf16x8 ah0 = *(const bf16x8*)(ap);
    bf16x8 ah1 = *(const bf16x8*)(ap + 32);
    bf16x8 al0 = *(const bf16x8*)(ap + 64);
    bf16x8 al1 = *(const bf16x8*)(ap + 96);

    unsigned int tk[4][5];
    #pragma unroll
    for (int r=0;r<4;++r)
        #pragma unroll
        for (int kk=0;kk<5;++kk) tk[r][kk] = 0u;

    int colbase = ce*512;
    unsigned int inv0 = 4095u - (unsigned int)(colbase + ln);

    const unsigned short* bp = hb + (size_t)(colbase + ln)*128 + kh*8;
    // double-buffered B fragments (named regs, static indexing)
    bf16x8 Ah0 = *(const bf16x8*)(bp);
    bf16x8 Ah1 = *(const bf16x8*)(bp + 32);
    bf16x8 Al0 = *(const bf16x8*)(bp + 64);
    bf16x8 Al1 = *(const bf16x8*)(bp + 96);
    bf16x8 Bh0, Bh1, Bl0, Bl1;

    for (int t5 = 0; t5 < 32; t5 += 2) {
        {   // prefetch t5+1
            const unsigned short* p = bp + (size_t)(t5+1)*16*128;
            Bh0 = *(const bf16x8*)(p);
            Bh1 = *(const bf16x8*)(p + 32);
            Bl0 = *(const bf16x8*)(p + 64);
            Bl1 = *(const bf16x8*)(p + 96);
        }
        ctile(ah0,ah1,al0,al1, Ah0,Ah1,Al0,Al1, tk, inv0 - (unsigned int)(t5*16));
        {   // prefetch t5+2 (clamped on last iter; dummy, unused)
            int m = (t5+2 < 32) ? (t5+2) : 0;
            const unsigned short* p = bp + (size_t)m*16*128;
            Ah0 = *(const bf16x8*)(p);
            Ah1 = *(const bf16x8*)(p + 32);
            Al0 = *(const bf16x8*)(p + 64);
            Al1 = *(const bf16x8*)(p + 96);
        }
        ctile(ah0,ah1,al0,al1, Bh0,Bh1,Bl0,Bl1, tk, inv0 - (unsigned int)((t5+1)*16));
    }

    // butterfly merge across the 16 column-lanes (lane bits 0..3 = ln)
    #pragma unroll
    for (int m = 1; m < 16; m <<= 1) {
        #pragma unroll
        for (int r=0;r<4;++r) {
            unsigned int ok[5];
            #pragma unroll
            for (int kk=0;kk<5;++kk)
                ok[kk] = (unsigned int)__shfl_xor((int)tk[r][kk], m);
            #pragma unroll
            for (int kk=0;kk<5;++kk) ins5k(tk[r], ok[kk]);
        }
    }
    if (ln == 0) {
        #pragma unroll
        for (int r=0;r<4;++r) {
            int row = rg*64 + wave*16 + kh*4 + r;    // C/D row for this lane/reg
            size_t base = (((size_t)b*NN + row)*8 + ce)*5;
            #pragma unroll
            for (int kk=0;kk<5;++kk) pk[base+kk] = tk[r][kk];
        }
    }
}

// ---------- K4: fused top-5 merge + laplacian(k)·laplacian(v) partial reduction ----------
__global__ __launch_bounds__(256) void k_kv(const float* __restrict__ ko, const float* __restrict__ vo,
                                            const unsigned int* __restrict__ pk, float* __restrict__ part)
{
    int blk = blockIdx.x;                 // bh(16) * chunk(16)
    int chunk = blk & 15, bh = blk >> 4, b = bh >> 2;
    int t = threadIdx.x;
    __shared__ int idxl[256][5];
    __shared__ float red[4][64];
    {   // merge the 8 column-eighth partials for this chunk's 256 nodes
        int n = chunk*256 + t;
        const uint4* pp = (const uint4*)(pk + ((size_t)b*NN + n)*40);
        unsigned int bk5[5] = {0u,0u,0u,0u,0u};
        #pragma unroll
        for (int e = 0; e < 10; ++e) {
            uint4 v4 = pp[e];
            ins5k(bk5, v4.x); ins5k(bk5, v4.y); ins5k(bk5, v4.z); ins5k(bk5, v4.w);
        }
        #pragma unroll
        for (int kk=0;kk<5;++kk) idxl[t][kk] = 4095 - (int)(bk5[kk] & 0xFFFu);
    }
    __syncthreads();
    int f = t & 63, g = t >> 6;
    const float* kb = ko + (size_t)bh*NN*64;
    const float* vb = vo + (size_t)bh*NN*64;
    float acc = 0.f;
    for (int i2 = 0; i2 < 64; ++i2) {
        int nl = g*64 + i2;
        int n = chunk*256 + nl;
        const int* ip = idxl[nl];
        int j0 = ip[0], j1 = ip[1], j2 = ip[2], j3 = ip[3], j4 = ip[4];
        float lk = kb[(size_t)n*64+f] + kb[(size_t)j0*64+f] + kb[(size_t)j1*64+f]
                 + kb[(size_t)j2*64+f] + kb[(size_t)j3*64+f] + kb[(size_t)j4*64+f];
        float lv = vb[(size_t)n*64+f] + vb[(size_t)j0*64+f] + vb[(size_t)j1*64+f]
                 + vb[(size_t)j2*64+f] + vb[(size_t)j3*64+f] + vb[(size_t)j4*64+f];
        acc += lk*lv;
    }
    red[g][f] = acc;
    __syncthreads();
    if (t < 64) {
        float s2 = red[0][t] + red[1][t] + red[2][t] + red[3][t];
        part[((size_t)bh*64 + t)*16 + chunk] = s2;
    }
}

// ---------- K5: wps[b][o][hf] = wp[o][hf] * kv[b][hf]/36 ----------
__global__ __launch_bounds__(256) void k_wps(const float* __restrict__ wp, const float* __restrict__ part,
                                             float* __restrict__ wps)
{
    int t = blockIdx.x*256 + threadIdx.x;    // 65536 = b(4)*o(64)*hf(256)
    int b = t >> 14, rem = t & 16383;
    int hf = rem & 255;
    const float* pp = part + ((size_t)b*256 + hf)*16;
    float s = 0.f;
    #pragma unroll
    for (int c2 = 0; c2 < 16; ++c2) s += pp[c2];
    wps[t] = wp[rem] * (s * (1.f/36.f));
}

// ---------- K6: fused (hy·wp) conv + conv1/BN/ReLU + conv2/BN/ReLU ----------
__global__ __launch_bounds__(256) void k_out(
    const float* __restrict__ qo, const float* __restrict__ wpsb, const float* __restrict__ bp,
    const float* __restrict__ w1, const float* __restrict__ b1,
    const float* __restrict__ w2, const float* __restrict__ b2,
    const float* __restrict__ g1, const float* __restrict__ be1,
    const float* __restrict__ m1, const float* __restrict__ v1,
    const float* __restrict__ g2, const float* __restrict__ be2,
    const float* __restrict__ m2, const float* __restrict__ v2,
    float* __restrict__ outp)
{
    int b  = blockIdx.x >> 6;
    int n0 = (blockIdx.x & 63)*64;
    __shared__ __align__(16) float qs[256*68];   // q tile [hf][nl]; later t1 [o][nl]
    __shared__ __align__(16) float ws2[256*68];  // wps [hf][o]; later w1s/w2s [c][o]
    __shared__ __align__(16) float t0[64*68];    // conv_p out [o][nl]; later t2
    int t = threadIdx.x;
    {
        int f = t & 63, sub = t >> 6;
        #pragma unroll
        for (int h = 0; h < 4; ++h) {
            const float* qb = qo + (((size_t)(b*4+h))*NN + n0)*64 + f;
            for (int nl = sub; nl < 64; nl += 4)
                qs[(h*64+f)*68 + nl] = qb[(size_t)nl*64];
        }
    }
    {
        const float* wb = wpsb + (size_t)b*64*256;
        for (int o = 0; o < 64; ++o)
            ws2[t*68 + o] = wb[(size_t)o*256 + t];
    }
    __syncthreads();
    int tr = t >> 4, tc = t & 15;
    float acc[4][4];
    #pragma unroll
    for (int i=0;i<4;++i) {
        float bb = bp[tr*4+i];
        #pragma unroll
        for (int j=0;j<4;++j) acc[i][j] = bb;
    }
    #pragma unroll 8
    for (int hf = 0; hf < 256; ++hf) {
        float4 a4 = *(const float4*)&ws2[hf*68 + tr*4];
        float4 b4 = *(const float4*)&qs[hf*68 + tc*4];
        float av[4]={a4.x,a4.y,a4.z,a4.w}, bvv[4]={b4.x,b4.y,b4.z,b4.w};
        #pragma unroll
        for (int i=0;i<4;++i)
            #pragma unroll
            for (int j=0;j<4;++j)
                acc[i][j] += av[i]*bvv[j];
    }
    #pragma unroll
    for (int i=0;i<4;++i)
        *(float4*)&t0[(tr*4+i)*68 + tc*4] = make_float4(acc[i][0],acc[i][1],acc[i][2],acc[i][3]);
    __syncthreads();
    #pragma unroll
    for (int s = 0; s < 16; ++s) {   // w1 transposed into ws2
        int e = t + 256*s;
        ws2[(e & 63)*68 + (e >> 6)] = w1[e];
    }
    __syncthreads();
    float acc2[4][4];
    #pragma unroll
    for (int i=0;i<4;++i)
        #pragma unroll
        for (int j=0;j<4;++j) acc2[i][j] = 0.f;
    #pragma unroll 8
    for (int c = 0; c < 64; ++c) {
        float4 a4 = *(const float4*)&ws2[c*68 + tr*4];
        float4 b4 = *(const float4*)&t0[c*68 + tc*4];
        float av[4]={a4.x,a4.y,a4.z,a4.w}, bvv[4]={b4.x,b4.y,b4.z,b4.w};
        #pragma unroll
        for (int i=0;i<4;++i)
            #pragma unroll
            for (int j=0;j<4;++j)
                acc2[i][j] += av[i]*bvv[j];
    }
    #pragma unroll
    for (int i=0;i<4;++i) {          // BN1 + ReLU -> t1 (in qs region)
        int o = tr*4+i;
        float sc = g1[o] / sqrtf(v1[o] + 1e-5f);
        float bb = b1[o], mm = m1[o], bt = be1[o];
        float4 r;
        r.x = fmaxf((acc2[i][0]+bb-mm)*sc + bt, 0.f);
        r.y = fmaxf((acc2[i][1]+bb-mm)*sc + bt, 0.f);
        r.z = fmaxf((acc2[i][2]+bb-mm)*sc + bt, 0.f);
        r.w = fmaxf((acc2[i][3]+bb-mm)*sc + bt, 0.f);
        *(float4*)&qs[o*68 + tc*4] = r;
    }
    __syncthreads();
    #pragma unroll
    for (int s = 0; s < 16; ++s) {   // w2 transposed into ws2
        int e = t + 256*s;
        ws2[(e & 63)*68 + (e >> 6)] = w2[e];
    }
    __syncthreads();
    float acc3[4][4];
    #pragma unroll
    for (int i=0;i<4;++i)
        #pragma unroll
        for (int j=0;j<4;++j) acc3[i][j] = 0.f;
    #pragma unroll 8
    for (int c = 0; c < 64; ++c) {
        float4 a4 = *(const float4*)&ws2[c*68 + tr*4];
        float4 b4 = *(const float4*)&qs[c*68 + tc*4];
        float av[4]={a4.x,a4.y,a4.z,a4.w}, bvv[4]={b4.x,b4.y,b4.z,b4.w};
        #pragma unroll
        for (int i=0;i<4;++i)
            #pragma unroll
            for (int j=0;j<4;++j)
                acc3[i][j] += av[i]*bvv[j];
    }
    #pragma unroll
    for (int i=0;i<4;++i) {          // BN2 + ReLU -> t2 (in t0 region)
        int o = tr*4+i;
        float sc = g2[o] / sqrtf(v2[o] + 1e-5f);
        float bb = b2[o], mm = m2[o], bt = be2[o];
        float4 r;
        r.x = fmaxf((acc3[i][0]+bb-mm)*sc + bt, 0.f);
        r.y = fmaxf((acc3[i][1]+bb-mm)*sc + bt, 0.f);
        r.z = fmaxf((acc3[i][2]+bb-mm)*sc + bt, 0.f);
        r.w = fmaxf((acc3[i][3]+bb-mm)*sc + bt, 0.f);
        *(float4*)&t0[o*68 + tc*4] = r;
    }
    __syncthreads();
    float* ob = outp + ((size_t)b*64)*NN + n0;
    #pragma unroll
    for (int s = 0; s < 16; ++s) {
        int e = t + 256*s;
        int o = e >> 6, nl = e & 63;
        ob[(size_t)o*NN + nl] = t0[o*68 + nl];
    }
}

extern "C" void kernel_launch(void* const* d_in, const int* in_sizes, int n_in,
                              void* d_out, int out_size, void* d_ws, size_t ws_size,
                              hipStream_t stream)
{
    (void)in_sizes; (void)n_in; (void)out_size; (void)ws_size;
    const float* x  = (const float*)d_in[0];
    const float* wk = (const float*)d_in[1];
    const float* bk = (const float*)d_in[2];
    const float* wq = (const float*)d_in[3];
    const float* bq = (const float*)d_in[4];
    const float* wv = (const float*)d_in[5];
    const float* bv = (const float*)d_in[6];
    const float* wp = (const float*)d_in[7];
    const float* bp = (const float*)d_in[8];
    const float* w1 = (const float*)d_in[9];
    const float* b1 = (const float*)d_in[10];
    const float* w2 = (const float*)d_in[11];
    const float* b2 = (const float*)d_in[12];
    const float* g1 = (const float*)d_in[13];
    const float* be1= (const float*)d_in[14];
    const float* m1 = (const float*)d_in[15];
    const float* v1 = (const float*)d_in[16];
    const float* g2 = (const float*)d_in[17];
    const float* be2= (const float*)d_in[18];
    const float* m2 = (const float*)d_in[19];
    const float* v2 = (const float*)d_in[20];
    float* out = (float*)d_out;

    float* ws = (float*)d_ws;
    unsigned short* hlb = (unsigned short*)ws;  ws += (size_t)NB*NN*128/2;  // 4MB interleaved hi|lo
    float* qbuf = ws;  ws += (size_t)NB*NH*NN*64;     // 16MB
    float* kbuf = ws;  ws += (size_t)NB*NH*NN*64;
    float* vbuf = ws;  ws += (size_t)NB*NH*NN*64;
    float* wps  = ws;  ws += (size_t)NB*64*256;
    float* part = ws;  ws += (size_t)16*64*16;
    unsigned int* pk = (unsigned int*)ws;  ws += (size_t)NB*NN*40;  // 655,360 u32

    k_xsplit<<<64, 256, 0, stream>>>(x, hlb);
    k_qkv<<<3072, 256, 0, stream>>>(x, wk,bk, wq,bq, wv,bv, qbuf,kbuf,vbuf);
    k_topk<<<2048, 256, 0, stream>>>(hlb, pk);
    k_kv<<<256, 256, 0, stream>>>(kbuf, vbuf, pk, part);
    k_wps<<<256, 256, 0, stream>>>(wp, part, wps);
    k_out<<<256, 256, 0, stream>>>(qbuf, wps, bp, w1,b1, w2,b2,
                                   g1,be1,m1,v1, g2,be2,m2,v2, out);
}

// Round 6
// 160.308 us; speedup vs baseline: 2.3884x; 1.4410x over previous
//
#include <hip/hip_runtime.h>
#include <math.h>

#define NB 4
#define NC 64
#define NN 4096
#define NH 4

typedef __attribute__((ext_vector_type(8))) short bf16x8;
typedef __attribute__((ext_vector_type(4))) float f32x4;

// ---------- RNE float -> bf16 bits ----------
__device__ __forceinline__ unsigned int bf16rne(float v) {
    unsigned int u = __float_as_uint(v);
    return (u + 0x7fffu + ((u >> 16) & 1u)) >> 16;
}

// ---------- top-5 insert via min/max sorting network (9 VALU, no masks) ----------
__device__ __forceinline__ void ins5k(unsigned int (&tk)[5], unsigned int key) {
    unsigned int hi0 = max(tk[0], key), lo0 = min(tk[0], key); tk[0] = hi0;
    unsigned int hi1 = max(tk[1], lo0), lo1 = min(tk[1], lo0); tk[1] = hi1;
    unsigned int hi2 = max(tk[2], lo1), lo2 = min(tk[2], lo1); tk[2] = hi2;
    unsigned int hi3 = max(tk[3], lo2), lo3 = min(tk[3], lo2); tk[3] = hi3;
    tk[4] = max(tk[4], lo3);
}

// ---------- K1: channel-l2-normalize x -> interleaved [hi(64)|lo(64)] bf16 per node ----------
__global__ __launch_bounds__(256) void k_xsplit(const float* __restrict__ x,
                                                unsigned short* __restrict__ hl) {
    int t = blockIdx.x*256 + threadIdx.x;        // (b,n)
    int b = t >> 12, n = t & (NN-1);
    const float* xb = x + (size_t)b*NC*NN + n;
    float vals[64];
    float ss = 0.f;
    #pragma unroll
    for (int c = 0; c < NC; ++c) { vals[c] = xb[(size_t)c*NN]; ss += vals[c]*vals[c]; }
    float rn = 1.f / fmaxf(sqrtf(ss), 1e-12f);
    unsigned short* ho = hl + (size_t)t*128;
    #pragma unroll
    for (int g = 0; g < 8; ++g) {
        unsigned int hw[4], lw[4];
        #pragma unroll
        for (int p = 0; p < 4; ++p) {
            float v0 = vals[g*8 + p*2]     * rn;
            float v1 = vals[g*8 + p*2 + 1] * rn;
            unsigned int h0 = bf16rne(v0), h1 = bf16rne(v1);
            float r0 = v0 - __uint_as_float(h0 << 16);
            float r1 = v1 - __uint_as_float(h1 << 16);
            unsigned int l0 = bf16rne(r0), l1 = bf16rne(r1);
            hw[p] = h0 | (h1 << 16);
            lw[p] = l0 | (l1 << 16);
        }
        *(uint4*)(ho + g*8)      = make_uint4(hw[0], hw[1], hw[2], hw[3]);
        *(uint4*)(ho + 64 + g*8) = make_uint4(lw[0], lw[1], lw[2], lw[3]);
    }
}

// ---------- K2: q/k/v projections + fused l2norm (q,k); output (b,h,n,f), f contiguous ----------
__global__ __launch_bounds__(256) void k_qkv(
    const float* __restrict__ x,
    const float* __restrict__ wk, const float* __restrict__ bk,
    const float* __restrict__ wq, const float* __restrict__ bq,
    const float* __restrict__ wv, const float* __restrict__ bv,
    float* __restrict__ qo, float* __restrict__ ko, float* __restrict__ vo)
{
    int blk = blockIdx.x;
    int nt  = blk & 63;
    int rem = blk >> 6;          // 0..47
    int ot  = rem % 12;
    int b   = rem / 12;
    int mat = ot >> 2, h = ot & 3;
    const float* w    = (mat==0) ? wk : ((mat==1) ? wq : wv);
    const float* bias = (mat==0) ? bk : ((mat==1) ? bq : bv);
    float* outp       = (mat==0) ? ko : ((mat==1) ? qo : vo);

    __shared__ __align__(16) float As[64*68];   // [c][f]
    __shared__ __align__(16) float Bs[64*68];   // [c][nl]
    __shared__ float redq[16][64];
    __shared__ float rnl[64];
    int t = threadIdx.x;
    int n0 = nt*64;
    {   // stage transposed weight tile
        int f = t >> 2, q4 = t & 3;
        #pragma unroll
        for (int s = 0; s < 4; ++s) {
            int c0 = q4*16 + s*4;
            float4 w4 = *(const float4*)(w + (size_t)(h*64+f)*64 + c0);
            As[(c0+0)*68+f] = w4.x; As[(c0+1)*68+f] = w4.y;
            As[(c0+2)*68+f] = w4.z; As[(c0+3)*68+f] = w4.w;
        }
    }
    {   // stage x tile
        int u = t & 15, cb = t >> 4;
        #pragma unroll
        for (int s = 0; s < 4; ++s) {
            int c = cb + 16*s;
            float4 x4 = *(const float4*)(x + ((size_t)b*NC + c)*NN + n0 + u*4);
            *(float4*)&Bs[c*68 + u*4] = x4;
        }
    }
    __syncthreads();
    int tr = t >> 4, tc = t & 15;
    float acc[4][4];
    #pragma unroll
    for (int i=0;i<4;++i) {
        float bb = bias[h*64 + tr*4 + i];
        #pragma unroll
        for (int j=0;j<4;++j) acc[i][j] = bb;
    }
    #pragma unroll 8
    for (int c = 0; c < 64; ++c) {
        float4 a4 = *(const float4*)&As[c*68 + tr*4];
        float4 b4 = *(const float4*)&Bs[c*68 + tc*4];
        float av[4]  = {a4.x,a4.y,a4.z,a4.w};
        float bvv[4] = {b4.x,b4.y,b4.z,b4.w};
        #pragma unroll
        for (int i=0;i<4;++i)
            #pragma unroll
            for (int j=0;j<4;++j)
                acc[i][j] += av[i]*bvv[j];
    }
    if (mat != 2) {   // fused l2norm over f for q,k
        #pragma unroll
        for (int j=0;j<4;++j) {
            float s2 = acc[0][j]*acc[0][j] + acc[1][j]*acc[1][j]
                     + acc[2][j]*acc[2][j] + acc[3][j]*acc[3][j];
            redq[tr][tc*4+j] = s2;
        }
        __syncthreads();
        if (t < 64) {
            float s2 = 0.f;
            #pragma unroll
            for (int q = 0; q < 16; ++q) s2 += redq[q][t];
            rnl[t] = 1.f / fmaxf(sqrtf(s2), 1e-12f);
        }
        __syncthreads();
        #pragma unroll
        for (int j=0;j<4;++j) {
            float rr = rnl[tc*4+j];
            #pragma unroll
            for (int i=0;i<4;++i) acc[i][j] *= rr;
        }
    }
    float* ob = outp + (((size_t)(b*NH + h))*NN + n0)*64;
    #pragma unroll
    for (int j=0;j<4;++j) {
        float4 o4 = make_float4(acc[0][j], acc[1][j], acc[2][j], acc[3][j]);
        *(float4*)(ob + (size_t)(tc*4+j)*64 + tr*4) = o4;   // [n][f], f contiguous
    }
}

// ---------- K3: MFMA split-bf16 sim + packed-key min/max top-5 ----------
// Grid = b(4) x rowgroup(32 of 128 rows) x coleighth(8) = 1024 blocks, 256 thr.
// Wave owns 32 rows (2 strips of 16): 12 MFMA (2 indep chains) per B-tile load.
// key = bits(sim+2.0)[31:12] | (4095-col) : unsigned cmp == (value desc, col asc).
__device__ __forceinline__ void ctile(const bf16x8& ah0, const bf16x8& ah1,
                                      const bf16x8& al0, const bf16x8& al1,
                                      const bf16x8& bh0, const bf16x8& bh1,
                                      const bf16x8& bl0, const bf16x8& bl1,
                                      unsigned int (&tk)[4][5], unsigned int inv)
{
    f32x4 acc = {0.f, 0.f, 0.f, 0.f};
    acc = __builtin_amdgcn_mfma_f32_16x16x32_bf16(ah0, bh0, acc, 0,0,0);
    acc = __builtin_amdgcn_mfma_f32_16x16x32_bf16(ah1, bh1, acc, 0,0,0);
    acc = __builtin_amdgcn_mfma_f32_16x16x32_bf16(al0, bh0, acc, 0,0,0);
    acc = __builtin_amdgcn_mfma_f32_16x16x32_bf16(al1, bh1, acc, 0,0,0);
    acc = __builtin_amdgcn_mfma_f32_16x16x32_bf16(ah0, bl0, acc, 0,0,0);
    acc = __builtin_amdgcn_mfma_f32_16x16x32_bf16(ah1, bl1, acc, 0,0,0);
    #pragma unroll
    for (int r = 0; r < 4; ++r) {
        unsigned int key = (__float_as_uint(acc[r] + 2.0f) & 0xFFFFF000u) | inv;
        ins5k(tk[r], key);
    }
}

__global__ __launch_bounds__(256, 4) void k_topk(const unsigned short* __restrict__ hl,
                                                 unsigned int* __restrict__ pk)
{
    int blk = blockIdx.x;
    int ce = blk & 7;
    int rg = (blk >> 3) & 31;
    int b  = blk >> 8;
    int t = threadIdx.x, lane = t & 63, wave = t >> 6;
    int ln = lane & 15, kh = lane >> 4;
    const unsigned short* hb = hl + (size_t)b*NN*128;

    // two A strips: rows rg*128 + wave*32 + {0,16} + ln
    const unsigned short* ap0 = hb + (size_t)(rg*128 + wave*32 + ln)*128 + kh*8;
    const unsigned short* ap1 = ap0 + 16*128;
    bf16x8 a0h0 = *(const bf16x8*)(ap0);
    bf16x8 a0h1 = *(const bf16x8*)(ap0 + 32);
    bf16x8 a0l0 = *(const bf16x8*)(ap0 + 64);
    bf16x8 a0l1 = *(const bf16x8*)(ap0 + 96);
    bf16x8 a1h0 = *(const bf16x8*)(ap1);
    bf16x8 a1h1 = *(const bf16x8*)(ap1 + 32);
    bf16x8 a1l0 = *(const bf16x8*)(ap1 + 64);
    bf16x8 a1l1 = *(const bf16x8*)(ap1 + 96);

    unsigned int tkA[4][5], tkB[4][5];
    #pragma unroll
    for (int r=0;r<4;++r)
        #pragma unroll
        for (int kk=0;kk<5;++kk) { tkA[r][kk] = 0u; tkB[r][kk] = 0u; }

    int colbase = ce*512;
    unsigned int inv0 = 4095u - (unsigned int)(colbase + ln);

    const unsigned short* bp = hb + (size_t)(colbase + ln)*128 + kh*8;
    // double-buffered B fragments (named regs, static indexing)
    bf16x8 Ah0 = *(const bf16x8*)(bp);
    bf16x8 Ah1 = *(const bf16x8*)(bp + 32);
    bf16x8 Al0 = *(const bf16x8*)(bp + 64);
    bf16x8 Al1 = *(const bf16x8*)(bp + 96);
    bf16x8 Bh0, Bh1, Bl0, Bl1;

    for (int t5 = 0; t5 < 32; t5 += 2) {
        {   // prefetch t5+1
            const unsigned short* p = bp + (size_t)(t5+1)*16*128;
            Bh0 = *(const bf16x8*)(p);
            Bh1 = *(const bf16x8*)(p + 32);
            Bl0 = *(const bf16x8*)(p + 64);
            Bl1 = *(const bf16x8*)(p + 96);
        }
        {
            unsigned int inv = inv0 - (unsigned int)(t5*16);
            ctile(a0h0,a0h1,a0l0,a0l1, Ah0,Ah1,Al0,Al1, tkA, inv);
            ctile(a1h0,a1h1,a1l0,a1l1, Ah0,Ah1,Al0,Al1, tkB, inv);
        }
        {   // prefetch t5+2 (clamped on last iter; dummy, unused)
            int m = (t5+2 < 32) ? (t5+2) : 0;
            const unsigned short* p = bp + (size_t)m*16*128;
            Ah0 = *(const bf16x8*)(p);
            Ah1 = *(const bf16x8*)(p + 32);
            Al0 = *(const bf16x8*)(p + 64);
            Al1 = *(const bf16x8*)(p + 96);
        }
        {
            unsigned int inv = inv0 - (unsigned int)((t5+1)*16);
            ctile(a0h0,a0h1,a0l0,a0l1, Bh0,Bh1,Bl0,Bl1, tkA, inv);
            ctile(a1h0,a1h1,a1l0,a1l1, Bh0,Bh1,Bl0,Bl1, tkB, inv);
        }
    }

    // butterfly merge across the 16 column-lanes (lane bits 0..3 = ln)
    #pragma unroll
    for (int m = 1; m < 16; m <<= 1) {
        #pragma unroll
        for (int r=0;r<4;++r) {
            unsigned int okA[5], okB[5];
            #pragma unroll
            for (int kk=0;kk<5;++kk) {
                okA[kk] = (unsigned int)__shfl_xor((int)tkA[r][kk], m);
                okB[kk] = (unsigned int)__shfl_xor((int)tkB[r][kk], m);
            }
            #pragma unroll
            for (int kk=0;kk<5;++kk) { ins5k(tkA[r], okA[kk]); ins5k(tkB[r], okB[kk]); }
        }
    }
    if (ln == 0) {
        #pragma unroll
        for (int r=0;r<4;++r) {
            int row0 = rg*128 + wave*32 + kh*4 + r;        // strip 0 C/D row
            size_t base0 = (((size_t)b*NN + row0)*8 + ce)*5;
            size_t base1 = (((size_t)b*NN + row0 + 16)*8 + ce)*5;
            #pragma unroll
            for (int kk=0;kk<5;++kk) { pk[base0+kk] = tkA[r][kk]; pk[base1+kk] = tkB[r][kk]; }
        }
    }
}

// ---------- K4: fused top-5 merge + laplacian(k)·laplacian(v) partial reduction ----------
__global__ __launch_bounds__(256) void k_kv(const float* __restrict__ ko, const float* __restrict__ vo,
                                            const unsigned int* __restrict__ pk, float* __restrict__ part)
{
    int blk = blockIdx.x;                 // bh(16) * chunk(16)
    int chunk = blk & 15, bh = blk >> 4, b = bh >> 2;
    int t = threadIdx.x;
    __shared__ int idxl[256][5];
    __shared__ float red[4][64];
    {   // merge the 8 column-eighth partials for this chunk's 256 nodes
        int n = chunk*256 + t;
        const uint4* pp = (const uint4*)(pk + ((size_t)b*NN + n)*40);
        unsigned int bk5[5] = {0u,0u,0u,0u,0u};
        #pragma unroll
        for (int e = 0; e < 10; ++e) {
            uint4 v4 = pp[e];
            ins5k(bk5, v4.x); ins5k(bk5, v4.y); ins5k(bk5, v4.z); ins5k(bk5, v4.w);
        }
        #pragma unroll
        for (int kk=0;kk<5;++kk) idxl[t][kk] = 4095 - (int)(bk5[kk] & 0xFFFu);
    }
    __syncthreads();
    int f = t & 63, g = t >> 6;
    const float* kb = ko + (size_t)bh*NN*64;
    const float* vb = vo + (size_t)bh*NN*64;
    float acc = 0.f;
    for (int i2 = 0; i2 < 64; ++i2) {
        int nl = g*64 + i2;
        int n = chunk*256 + nl;
        const int* ip = idxl[nl];
        int j0 = ip[0], j1 = ip[1], j2 = ip[2], j3 = ip[3], j4 = ip[4];
        float lk = kb[(size_t)n*64+f] + kb[(size_t)j0*64+f] + kb[(size_t)j1*64+f]
                 + kb[(size_t)j2*64+f] + kb[(size_t)j3*64+f] + kb[(size_t)j4*64+f];
        float lv = vb[(size_t)n*64+f] + vb[(size_t)j0*64+f] + vb[(size_t)j1*64+f]
                 + vb[(size_t)j2*64+f] + vb[(size_t)j3*64+f] + vb[(size_t)j4*64+f];
        acc += lk*lv;
    }
    red[g][f] = acc;
    __syncthreads();
    if (t < 64) {
        float s2 = red[0][t] + red[1][t] + red[2][t] + red[3][t];
        part[((size_t)bh*64 + t)*16 + chunk] = s2;
    }
}

// ---------- K5: wps[b][o][hf] = wp[o][hf] * kv[b][hf]/36 ----------
__global__ __launch_bounds__(256) void k_wps(const float* __restrict__ wp, const float* __restrict__ part,
                                             float* __restrict__ wps)
{
    int t = blockIdx.x*256 + threadIdx.x;    // 65536 = b(4)*o(64)*hf(256)
    int b = t >> 14, rem = t & 16383;
    int hf = rem & 255;
    const float* pp = part + ((size_t)b*256 + hf)*16;
    float s = 0.f;
    #pragma unroll
    for (int c2 = 0; c2 < 16; ++c2) s += pp[c2];
    wps[t] = wp[rem] * (s * (1.f/36.f));
}

// ---------- K6: fused (hy·wp) conv + conv1/BN/ReLU + conv2/BN/ReLU ----------
__global__ __launch_bounds__(256) void k_out(
    const float* __restrict__ qo, const float* __restrict__ wpsb, const float* __restrict__ bp,
    const float* __restrict__ w1, const float* __restrict__ b1,
    const float* __restrict__ w2, const float* __restrict__ b2,
    const float* __restrict__ g1, const float* __restrict__ be1,
    const float* __restrict__ m1, const float* __restrict__ v1,
    const float* __restrict__ g2, const float* __restrict__ be2,
    const float* __restrict__ m2, const float* __restrict__ v2,
    float* __restrict__ outp)
{
    int b  = blockIdx.x >> 6;
    int n0 = (blockIdx.x & 63)*64;
    __shared__ __align__(16) float qs[256*68];   // q tile [hf][nl]; later t1 [o][nl]
    __shared__ __align__(16) float ws2[256*68];  // wps [hf][o]; later w1s/w2s [c][o]
    __shared__ __align__(16) float t0[64*68];    // conv_p out [o][nl]; later t2
    int t = threadIdx.x;
    {
        int f = t & 63, sub = t >> 6;
        #pragma unroll
        for (int h = 0; h < 4; ++h) {
            const float* qb = qo + (((size_t)(b*4+h))*NN + n0)*64 + f;
            for (int nl = sub; nl < 64; nl += 4)
                qs[(h*64+f)*68 + nl] = qb[(size_t)nl*64];
        }
    }
    {
        const float* wb = wpsb + (size_t)b*64*256;
        for (int o = 0; o < 64; ++o)
            ws2[t*68 + o] = wb[(size_t)o*256 + t];
    }
    __syncthreads();
    int tr = t >> 4, tc = t & 15;
    float acc[4][4];
    #pragma unroll
    for (int i=0;i<4;++i) {
        float bb = bp[tr*4+i];
        #pragma unroll
        for (int j=0;j<4;++j) acc[i][j] = bb;
    }
    #pragma unroll 8
    for (int hf = 0; hf < 256; ++hf) {
        float4 a4 = *(const float4*)&ws2[hf*68 + tr*4];
        float4 b4 = *(const float4*)&qs[hf*68 + tc*4];
        float av[4]={a4.x,a4.y,a4.z,a4.w}, bvv[4]={b4.x,b4.y,b4.z,b4.w};
        #pragma unroll
        for (int i=0;i<4;++i)
            #pragma unroll
            for (int j=0;j<4;++j)
                acc[i][j] += av[i]*bvv[j];
    }
    #pragma unroll
    for (int i=0;i<4;++i)
        *(float4*)&t0[(tr*4+i)*68 + tc*4] = make_float4(acc[i][0],acc[i][1],acc[i][2],acc[i][3]);
    __syncthreads();
    #pragma unroll
    for (int s = 0; s < 16; ++s) {   // w1 transposed into ws2
        int e = t + 256*s;
        ws2[(e & 63)*68 + (e >> 6)] = w1[e];
    }
    __syncthreads();
    float acc2[4][4];
    #pragma unroll
    for (int i=0;i<4;++i)
        #pragma unroll
        for (int j=0;j<4;++j) acc2[i][j] = 0.f;
    #pragma unroll 8
    for (int c = 0; c < 64; ++c) {
        float4 a4 = *(const float4*)&ws2[c*68 + tr*4];
        float4 b4 = *(const float4*)&t0[c*68 + tc*4];
        float av[4]={a4.x,a4.y,a4.z,a4.w}, bvv[4]={b4.x,b4.y,b4.z,b4.w};
        #pragma unroll
        for (int i=0;i<4;++i)
            #pragma unroll
            for (int j=0;j<4;++j)
                acc2[i][j] += av[i]*bvv[j];
    }
    #pragma unroll
    for (int i=0;i<4;++i) {          // BN1 + ReLU -> t1 (in qs region)
        int o = tr*4+i;
        float sc = g1[o] / sqrtf(v1[o] + 1e-5f);
        float bb = b1[o], mm = m1[o], bt = be1[o];
        float4 r;
        r.x = fmaxf((acc2[i][0]+bb-mm)*sc + bt, 0.f);
        r.y = fmaxf((acc2[i][1]+bb-mm)*sc + bt, 0.f);
        r.z = fmaxf((acc2[i][2]+bb-mm)*sc + bt, 0.f);
        r.w = fmaxf((acc2[i][3]+bb-mm)*sc + bt, 0.f);
        *(float4*)&qs[o*68 + tc*4] = r;
    }
    __syncthreads();
    #pragma unroll
    for (int s = 0; s < 16; ++s) {   // w2 transposed into ws2
        int e = t + 256*s;
        ws2[(e & 63)*68 + (e >> 6)] = w2[e];
    }
    __syncthreads();
    float acc3[4][4];
    #pragma unroll
    for (int i=0;i<4;++i)
        #pragma unroll
        for (int j=0;j<4;++j) acc3[i][j] = 0.f;
    #pragma unroll 8
    for (int c = 0; c < 64; ++c) {
        float4 a4 = *(const float4*)&ws2[c*68 + tr*4];
        float4 b4 = *(const float4*)&qs[c*68 + tc*4];
        float av[4]={a4.x,a4.y,a4.z,a4.w}, bvv[4]={b4.x,b4.y,b4.z,b4.w};
        #pragma unroll
        for (int i=0;i<4;++i)
            #pragma unroll
            for (int j=0;j<4;++j)
                acc3[i][j] += av[i]*bvv[j];
    }
    #pragma unroll
    for (int i=0;i<4;++i) {          // BN2 + ReLU -> t2 (in t0 region)
        int o = tr*4+i;
        float sc = g2[o] / sqrtf(v2[o] + 1e-5f);
        float bb = b2[o], mm = m2[o], bt = be2[o];
        float4 r;
        r.x = fmaxf((acc3[i][0]+bb-mm)*sc + bt, 0.f);
        r.y = fmaxf((acc3[i][1]+bb-mm)*sc + bt, 0.f);
        r.z = fmaxf((acc3[i][2]+bb-mm)*sc + bt, 0.f);
        r.w = fmaxf((acc3[i][3]+bb-mm)*sc + bt, 0.f);
        *(float4*)&t0[o*68 + tc*4] = r;
    }
    __syncthreads();
    float* ob = outp + ((size_t)b*64)*NN + n0;
    #pragma unroll
    for (int s = 0; s < 16; ++s) {
        int e = t + 256*s;
        int o = e >> 6, nl = e & 63;
        ob[(size_t)o*NN + nl] = t0[o*68 + nl];
    }
}

extern "C" void kernel_launch(void* const* d_in, const int* in_sizes, int n_in,
                              void* d_out, int out_size, void* d_ws, size_t ws_size,
                              hipStream_t stream)
{
    (void)in_sizes; (void)n_in; (void)out_size; (void)ws_size;
    const float* x  = (const float*)d_in[0];
    const float* wk = (const float*)d_in[1];
    const float* bk = (const float*)d_in[2];
    const float* wq = (const float*)d_in[3];
    const float* bq = (const float*)d_in[4];
    const float* wv = (const float*)d_in[5];
    const float* bv = (const float*)d_in[6];
    const float* wp = (const float*)d_in[7];
    const float* bp = (const float*)d_in[8];
    const float* w1 = (const float*)d_in[9];
    const float* b1 = (const float*)d_in[10];
    const float* w2 = (const float*)d_in[11];
    const float* b2 = (const float*)d_in[12];
    const float* g1 = (const float*)d_in[13];
    const float* be1= (const float*)d_in[14];
    const float* m1 = (const float*)d_in[15];
    const float* v1 = (const float*)d_in[16];
    const float* g2 = (const float*)d_in[17];
    const float* be2= (const float*)d_in[18];
    const float* m2 = (const float*)d_in[19];
    const float* v2 = (const float*)d_in[20];
    float* out = (float*)d_out;

    float* ws = (float*)d_ws;
    unsigned short* hlb = (unsigned short*)ws;  ws += (size_t)NB*NN*128/2;  // 4MB interleaved hi|lo
    float* qbuf = ws;  ws += (size_t)NB*NH*NN*64;     // 16MB
    float* kbuf = ws;  ws += (size_t)NB*NH*NN*64;
    float* vbuf = ws;  ws += (size_t)NB*NH*NN*64;
    float* wps  = ws;  ws += (size_t)NB*64*256;
    float* part = ws;  ws += (size_t)16*64*16;
    unsigned int* pk = (unsigned int*)ws;  ws += (size_t)NB*NN*40;  // 655,360 u32

    k_xsplit<<<64, 256, 0, stream>>>(x, hlb);
    k_qkv<<<3072, 256, 0, stream>>>(x, wk,bk, wq,bq, wv,bv, qbuf,kbuf,vbuf);
    k_topk<<<1024, 256, 0, stream>>>(hlb, pk);
    k_kv<<<256, 256, 0, stream>>>(kbuf, vbuf, pk, part);
    k_wps<<<256, 256, 0, stream>>>(wp, part, wps);
    k_out<<<256, 256, 0, stream>>>(qbuf, wps, bp, w1,b1, w2,b2,
                                   g1,be1,m1,v1, g2,be2,m2,v2, out);
}